// Round 3
// baseline (341.616 us; speedup 1.0000x reference)
//
#include <hip/hip_runtime.h>
#include <math.h>

#define SS 7
#define NROIS 64
#define CC 2048
#define DD (SS*SS*CC)   // 100352
#define MM 64
#define NN 1024
#define KC1 49          // 49*2048 = 100352

typedef float f32x4 __attribute__((ext_vector_type(4)));
typedef __bf16 bf16x8 __attribute__((ext_vector_type(8)));

__device__ __forceinline__ unsigned short f2bf(float f){
    unsigned u = __builtin_bit_cast(unsigned, f);
    u += 0x7fffu + ((u >> 16) & 1u);           // RNE
    return (unsigned short)(u >> 16);
}
__device__ __forceinline__ float bf2f(unsigned short h){
    unsigned u = ((unsigned)h) << 16;
    return __builtin_bit_cast(float, u);
}
// native-cast hi/lo split, packed two-at-a-time (compiler emits cvt_pk)
__device__ __forceinline__ void splitpk(float v0, float v1, unsigned& h, unsigned& l){
    __bf16 h0 = (__bf16)v0, h1 = (__bf16)v1;
    float r0 = v0 - (float)h0, r1 = v1 - (float)h1;
    __bf16 l0 = (__bf16)r0, l1 = (__bf16)r1;
    h = (unsigned)__builtin_bit_cast(unsigned short, h0) |
        ((unsigned)__builtin_bit_cast(unsigned short, h1) << 16);
    l = (unsigned)__builtin_bit_cast(unsigned short, l0) |
        ((unsigned)__builtin_bit_cast(unsigned short, l1) << 16);
}

// ---------------- Stage 1: crop + bilinear resize -> bf16 hi/lo planes ------
__global__ void crop_kernel(const float* __restrict__ fm,
                            const float* __restrict__ boxes,
                            unsigned short* __restrict__ Xhi,
                            unsigned short* __restrict__ Xlo) {
    int roi = blockIdx.x;
    int p   = blockIdx.y;         // 0..48
    int sy = p / SS, sx = p % SS;
    const float* b = boxes + roi * 4;
    float x1 = fmaxf(0.f, rintf(b[0]));
    float y1 = fmaxf(0.f, rintf(b[1]));
    float x2 = fminf(15.f, rintf(b[2]));
    float y2 = fminf(15.f, rintf(b[3]));
    float h = y2 - y1, w = x2 - x1;
    float iy = ((sy + 0.5f) * h) / 7.0f - 0.5f;
    float ix = ((sx + 0.5f) * w) / 7.0f - 0.5f;
    iy = fminf(fmaxf(iy, 0.f), h - 1.f);
    ix = fminf(fmaxf(ix, 0.f), w - 1.f);
    float y0 = floorf(iy), x0 = floorf(ix);
    float fy = iy - y0,   fx = ix - x0;
    int y0i = (int)(y1 + y0);
    int y1i = min(y0i + 1, (int)(y1 + h - 1.f));
    int x0i = (int)(x1 + x0);
    int x1i = min(x0i + 1, (int)(x1 + w - 1.f));

    int c = threadIdx.x * 4;
    const float4 v00 = *(const float4*)(fm + ((size_t)(y0i*16 + x0i))*CC + c);
    const float4 v01 = *(const float4*)(fm + ((size_t)(y0i*16 + x1i))*CC + c);
    const float4 v10 = *(const float4*)(fm + ((size_t)(y1i*16 + x0i))*CC + c);
    const float4 v11 = *(const float4*)(fm + ((size_t)(y1i*16 + x1i))*CC + c);
    float gy = 1.f - fy, gx = 1.f - fx;
    float o[4];
    o[0] = (v00.x*gy + v10.x*fy)*gx + (v01.x*gy + v11.x*fy)*fx;
    o[1] = (v00.y*gy + v10.y*fy)*gx + (v01.y*gy + v11.y*fy)*fx;
    o[2] = (v00.z*gy + v10.z*fy)*gx + (v01.z*gy + v11.z*fy)*fx;
    o[3] = (v00.w*gy + v10.w*fy)*gx + (v01.w*gy + v11.w*fy)*fx;
    uint2 hv, lv;
    splitpk(o[0], o[1], hv.x, lv.x);
    splitpk(o[2], o[3], hv.y, lv.y);
    size_t off = (size_t)roi*DD + (size_t)p*CC + c;
    *(uint2*)(Xhi + off) = hv;
    *(uint2*)(Xlo + off) = lv;
}

// ---------------- Stage 2: generic FC via bf16x2-split MFMA -----------------
// grid (n-tiles of 64, k-chunks), 256 thr = 4 waves. Wave tile 64m x 16n.
// A (activations) read DIRECTLY from global bf16 hi/lo planes (L2/L3-hot);
// W (fp32) staged through LDS transposed with in-register hi/lo split.
// 3-term: D += Ah*Bh + Ah*Bl + Al*Bh.
__global__ __launch_bounds__(256)
void fc_mfma(const unsigned short* __restrict__ Ahi,
             const unsigned short* __restrict__ Alo,
             const float* __restrict__ Wm, float* __restrict__ P,
             int astride, int kchunk) {
    const int nb = blockIdx.x, kc = blockIdx.y;
    const int n0 = nb * 64;
    const int k0 = kc * kchunk;
    const int t = threadIdx.x;
    const int lane = t & 63, wv = t >> 6;
    const int kp = t & 15, no = t >> 4;      // W staging: k-pair, n-quad

    __shared__ unsigned short WTh[64][72];   // [n][k] transposed, hi
    __shared__ unsigned short WTl[64][72];   // lo

    f32x4 acc[4];
    #pragma unroll
    for (int i = 0; i < 4; ++i) acc[i] = (f32x4){0.f, 0.f, 0.f, 0.f};

    // per-thread A fragment bases: row = mf*16 + (lane&15), k-off (lane>>4)*8
    const unsigned short* ah[4];
    const unsigned short* al[4];
    #pragma unroll
    for (int mf = 0; mf < 4; ++mf) {
        size_t ro = (size_t)(mf*16 + (lane & 15)) * astride + (size_t)k0 + ((lane >> 4) * 8);
        ah[mf] = Ahi + ro;
        al[mf] = Alo + ro;
    }

    float4 wr0, wr1, wr2, wr3;
    const float* wbase = Wm + (size_t)k0 * NN + n0 + no * 4;
    {
        const float* p = wbase + (size_t)(2 * kp) * NN;
        wr0 = *(const float4*)(p);
        wr1 = *(const float4*)(p + NN);
        wr2 = *(const float4*)(p + 32 * NN);
        wr3 = *(const float4*)(p + 33 * NN);
    }

    const int nkt = kchunk >> 6;
    for (int kt = 0; kt < nkt; ++kt) {
        __syncthreads();
        // ---- stage W tile (fp32 -> bf16 hi/lo, transposed)
        {
            const float* a0 = (const float*)&wr0;   // k = 2kp
            const float* a1 = (const float*)&wr1;   // k = 2kp+1
            const float* a2 = (const float*)&wr2;   // k = 2kp+32
            const float* a3 = (const float*)&wr3;   // k = 2kp+33
            #pragma unroll
            for (int j = 0; j < 4; ++j) {
                int n = no * 4 + j;
                unsigned h, l;
                splitpk(a0[j], a1[j], h, l);
                *(unsigned*)&WTh[n][2*kp] = h;
                *(unsigned*)&WTl[n][2*kp] = l;
                splitpk(a2[j], a3[j], h, l);
                *(unsigned*)&WTh[n][2*kp + 32] = h;
                *(unsigned*)&WTl[n][2*kp + 32] = l;
            }
        }
        // ---- prefetch next W tile (in flight across MFMA phase)
        if (kt + 1 < nkt) {
            const float* p = wbase + (size_t)((kt + 1) * 64 + 2 * kp) * NN;
            wr0 = *(const float4*)(p);
            wr1 = *(const float4*)(p + NN);
            wr2 = *(const float4*)(p + 32 * NN);
            wr3 = *(const float4*)(p + 33 * NN);
        }
        __syncthreads();
        // ---- MFMA phase: 2 k-steps of 32; A straight from global
        const int kbase = kt * 64;
        #pragma unroll
        for (int ks = 0; ks < 2; ++ks) {
            const int kk = ks * 32 + (lane >> 4) * 8;
            bf16x8 Bh = *(const bf16x8*)&WTh[wv*16 + (lane & 15)][kk];
            bf16x8 Bl = *(const bf16x8*)&WTl[wv*16 + (lane & 15)][kk];
            #pragma unroll
            for (int mf = 0; mf < 4; ++mf) {
                bf16x8 Ah = *(const bf16x8*)(ah[mf] + kbase + ks * 32);
                bf16x8 Al = *(const bf16x8*)(al[mf] + kbase + ks * 32);
                acc[mf] = __builtin_amdgcn_mfma_f32_16x16x32_bf16(Ah, Bh, acc[mf], 0, 0, 0);
                acc[mf] = __builtin_amdgcn_mfma_f32_16x16x32_bf16(Ah, Bl, acc[mf], 0, 0, 0);
                acc[mf] = __builtin_amdgcn_mfma_f32_16x16x32_bf16(Al, Bh, acc[mf], 0, 0, 0);
            }
        }
    }
    // ---- write partials: D row = (lane>>4)*4 + i, col = lane&15
    const int oc  = n0 + wv * 16 + (lane & 15);
    const int orb = (lane >> 4) * 4;
    #pragma unroll
    for (int mf = 0; mf < 4; ++mf)
        #pragma unroll
        for (int i = 0; i < 4; ++i) {
            int m = mf * 16 + orb + i;
            P[((size_t)kc * MM + m) * NN + oc] = acc[mf][i];
        }
}

// ---------------- Stage 3a: reduce partials + bias + relu -> bf16 hi/lo -----
__global__ void reduce_bias_split(const float* __restrict__ P,
                                  const float* __restrict__ bias,
                                  unsigned short* __restrict__ Yhi,
                                  unsigned short* __restrict__ Ylo, int KC) {
    int idx = blockIdx.x * 256 + threadIdx.x;   // 0..65535
    int n = idx & (NN - 1);
    float s = bias[n];
    for (int kc = 0; kc < KC; ++kc) s += P[(size_t)kc * (MM*NN) + idx];
    s = fmaxf(s, 0.f);
    unsigned short h = f2bf(s);
    Yhi[idx] = h;
    Ylo[idx] = f2bf(s - bf2f(h));
}

// ---------------- Stage 3b: reduce partials + bias + relu -> fp32 -----------
__global__ void reduce_bias_relu(const float* __restrict__ P,
                                 const float* __restrict__ bias,
                                 float* __restrict__ Y, int KC) {
    int idx = blockIdx.x * 256 + threadIdx.x;
    int n = idx & (NN - 1);
    float s = bias[n];
    for (int kc = 0; kc < KC; ++kc) s += P[(size_t)kc * (MM*NN) + idx];
    Y[idx] = fmaxf(s, 0.f);
}

// ---------------- Stage 4: heads --------------------------------------------
__global__ void heads_kernel(const float* __restrict__ h2,
                             const float* __restrict__ Wc, const float* __restrict__ bc,
                             const float* __restrict__ Wb, const float* __restrict__ bb,
                             float* __restrict__ out) {
    int m = blockIdx.x;
    int t = threadIdx.x;   // 256
    float a[6] = {0,0,0,0,0,0};
    for (int k = t; k < 1024; k += 256) {
        float xv = h2[(size_t)m * 1024 + k];
        a[0] += xv * Wc[k*2 + 0];
        a[1] += xv * Wc[k*2 + 1];
        a[2] += xv * Wb[k*4 + 0];
        a[3] += xv * Wb[k*4 + 1];
        a[4] += xv * Wb[k*4 + 2];
        a[5] += xv * Wb[k*4 + 3];
    }
    __shared__ float red[6][256];
    #pragma unroll
    for (int j = 0; j < 6; ++j) red[j][t] = a[j];
    __syncthreads();
    for (int s = 128; s > 0; s >>= 1) {
        if (t < s) {
            #pragma unroll
            for (int j = 0; j < 6; ++j) red[j][t] += red[j][t + s];
        }
        __syncthreads();
    }
    if (t == 0) {
        float l0 = red[0][0] + bc[0], l1 = red[1][0] + bc[1];
        float mx = fmaxf(l0, l1);
        float e0 = expf(l0 - mx), e1 = expf(l1 - mx);
        float inv = 1.f / (e0 + e1);
        out[m*2 + 0] = e0 * inv;
        out[m*2 + 1] = e1 * inv;
        out[128 + m*4 + 0] = red[2][0] + bb[0];
        out[128 + m*4 + 1] = red[3][0] + bb[1];
        out[128 + m*4 + 2] = red[4][0] + bb[2];
        out[128 + m*4 + 3] = red[5][0] + bb[3];
    }
}

extern "C" void kernel_launch(void* const* d_in, const int* in_sizes, int n_in,
                              void* d_out, int out_size, void* d_ws, size_t ws_size,
                              hipStream_t stream) {
    const float* fm    = (const float*)d_in[0];
    const float* boxes = (const float*)d_in[1];
    const float* W1    = (const float*)d_in[2];
    const float* b1    = (const float*)d_in[3];
    const float* W2    = (const float*)d_in[4];
    const float* b2    = (const float*)d_in[5];
    const float* Wc    = (const float*)d_in[6];
    const float* bc    = (const float*)d_in[7];
    const float* Wb    = (const float*)d_in[8];
    const float* bb    = (const float*)d_in[9];
    float* out = (float*)d_out;
    char* ws = (char*)d_ws;

    const size_t XB = (size_t)NROIS * DD * sizeof(unsigned short);  // 12,845,056
    unsigned short* Xhi  = (unsigned short*)ws;
    unsigned short* Xlo  = (unsigned short*)(ws + XB);
    float*          P1   = (float*)(ws + 2 * XB);                   // 12,845,056 B
    unsigned short* h1hi = (unsigned short*)(ws + 3 * XB);          // 131,072 B
    unsigned short* h1lo = (unsigned short*)(ws + 3 * XB + 131072);
    float*          P2   = (float*)(ws + 3 * XB + 262144);          // 2,097,152 B
    float*          h2   = (float*)(ws + 3 * XB + 262144 + 2097152);
    // total ~41.2 MB of d_ws

    crop_kernel<<<dim3(NROIS, SS*SS), 512, 0, stream>>>(fm, boxes, Xhi, Xlo);
    fc_mfma<<<dim3(16, KC1), 256, 0, stream>>>(Xhi, Xlo, W1, P1, DD, 2048);
    reduce_bias_split<<<(MM*NN)/256, 256, 0, stream>>>(P1, b1, h1hi, h1lo, KC1);
    fc_mfma<<<dim3(16, 8), 256, 0, stream>>>(h1hi, h1lo, W2, P2, NN, 128);
    reduce_bias_relu<<<(MM*NN)/256, 256, 0, stream>>>(P2, b2, h2, 8);
    heads_kernel<<<NROIS, 256, 0, stream>>>(h2, Wc, bc, Wb, bb, out);
}

// Round 4
// 231.241 us; speedup vs baseline: 1.4773x; 1.4773x over previous
//
#include <hip/hip_runtime.h>
#include <math.h>

#define SS 7
#define NROIS 64
#define CC 2048
#define DD (SS*SS*CC)   // 100352
#define MM 64
#define NN 1024
#define KC1 49          // 49*2048 = 100352

typedef float f32x4 __attribute__((ext_vector_type(4)));
typedef __bf16 bf16x8 __attribute__((ext_vector_type(8)));
typedef unsigned int uintx4 __attribute__((ext_vector_type(4)));

__device__ __forceinline__ unsigned short f2bf(float f){
    unsigned u = __builtin_bit_cast(unsigned, f);
    u += 0x7fffu + ((u >> 16) & 1u);           // RNE
    return (unsigned short)(u >> 16);
}
__device__ __forceinline__ float bf2f(unsigned short h){
    unsigned u = ((unsigned)h) << 16;
    return __builtin_bit_cast(float, u);
}
__device__ __forceinline__ void splitpk(float v0, float v1, unsigned& h, unsigned& l){
    __bf16 h0 = (__bf16)v0, h1 = (__bf16)v1;
    float r0 = v0 - (float)h0, r1 = v1 - (float)h1;
    __bf16 l0 = (__bf16)r0, l1 = (__bf16)r1;
    h = (unsigned)__builtin_bit_cast(unsigned short, h0) |
        ((unsigned)__builtin_bit_cast(unsigned short, h1) << 16);
    l = (unsigned)__builtin_bit_cast(unsigned short, l0) |
        ((unsigned)__builtin_bit_cast(unsigned short, l1) << 16);
}

// ---------------- Stage 1: crop + bilinear resize -> bf16 hi/lo planes ------
__global__ void crop_kernel(const float* __restrict__ fm,
                            const float* __restrict__ boxes,
                            unsigned short* __restrict__ Xhi,
                            unsigned short* __restrict__ Xlo) {
    int roi = blockIdx.x;
    int p   = blockIdx.y;         // 0..48
    int sy = p / SS, sx = p % SS;
    const float* b = boxes + roi * 4;
    float x1 = fmaxf(0.f, rintf(b[0]));
    float y1 = fmaxf(0.f, rintf(b[1]));
    float x2 = fminf(15.f, rintf(b[2]));
    float y2 = fminf(15.f, rintf(b[3]));
    float h = y2 - y1, w = x2 - x1;
    float iy = ((sy + 0.5f) * h) / 7.0f - 0.5f;
    float ix = ((sx + 0.5f) * w) / 7.0f - 0.5f;
    iy = fminf(fmaxf(iy, 0.f), h - 1.f);
    ix = fminf(fmaxf(ix, 0.f), w - 1.f);
    float y0 = floorf(iy), x0 = floorf(ix);
    float fy = iy - y0,   fx = ix - x0;
    int y0i = (int)(y1 + y0);
    int y1i = min(y0i + 1, (int)(y1 + h - 1.f));
    int x0i = (int)(x1 + x0);
    int x1i = min(x0i + 1, (int)(x1 + w - 1.f));

    int c = threadIdx.x * 4;
    const float4 v00 = *(const float4*)(fm + ((size_t)(y0i*16 + x0i))*CC + c);
    const float4 v01 = *(const float4*)(fm + ((size_t)(y0i*16 + x1i))*CC + c);
    const float4 v10 = *(const float4*)(fm + ((size_t)(y1i*16 + x0i))*CC + c);
    const float4 v11 = *(const float4*)(fm + ((size_t)(y1i*16 + x1i))*CC + c);
    float gy = 1.f - fy, gx = 1.f - fx;
    float o[4];
    o[0] = (v00.x*gy + v10.x*fy)*gx + (v01.x*gy + v11.x*fy)*fx;
    o[1] = (v00.y*gy + v10.y*fy)*gx + (v01.y*gy + v11.y*fy)*fx;
    o[2] = (v00.z*gy + v10.z*fy)*gx + (v01.z*gy + v11.z*fy)*fx;
    o[3] = (v00.w*gy + v10.w*fy)*gx + (v01.w*gy + v11.w*fy)*fx;
    uint2 hv, lv;
    splitpk(o[0], o[1], hv.x, lv.x);
    splitpk(o[2], o[3], hv.y, lv.y);
    size_t off = (size_t)roi*DD + (size_t)p*CC + c;
    *(uint2*)(Xhi + off) = hv;
    *(uint2*)(Xlo + off) = lv;
}

// ---------------- Stage 2: generic FC via bf16x2-split MFMA -----------------
// grid (n-tiles of 64, k-chunks), 256 thr = 4 waves in 2x2 (32m x 32n each).
// Both A and W staged in LDS; W prefetched 2 tiles deep, A(X) 1 deep.
// 3-term: D += Ah*Bh + Ah*Bl + Al*Bh.
__global__ __launch_bounds__(256, 4)
void fc_mfma(const unsigned short* __restrict__ Ahi,
             const unsigned short* __restrict__ Alo,
             const float* __restrict__ Wm, float* __restrict__ P,
             int astride, int kchunk) {
    const int nb = blockIdx.x, kc = blockIdx.y;
    const int n0 = nb * 64;
    const int k0 = kc * kchunk;
    const int t = threadIdx.x;
    const int lane = t & 63, wv = t >> 6;
    const int wm = (wv & 1) * 32;            // wave m-half
    const int wn = (wv >> 1) * 32;           // wave n-half
    const int kp = t & 15, no = t >> 4;      // W staging: k-pair, n-quad
    const int xr = t >> 2, xc = t & 3;       // X staging: row, col-quarter

    __shared__ unsigned short WTh[64][72];   // [n][k] transposed, hi
    __shared__ unsigned short WTl[64][72];   // lo
    __shared__ unsigned short XSh[64][72];   // [m][k] hi
    __shared__ unsigned short XSl[64][72];   // lo

    f32x4 acc00 = {0,0,0,0}, acc01 = {0,0,0,0};
    f32x4 acc10 = {0,0,0,0}, acc11 = {0,0,0,0};

    const float* wbase = Wm + (size_t)k0 * NN + n0 + no * 4;
    const unsigned short* xhb = Ahi + (size_t)xr * astride + k0 + xc * 16;
    const unsigned short* xlb = Alo + (size_t)xr * astride + k0 + xc * 16;

    auto loadW = [&](int kt, float4& a, float4& b, float4& c, float4& d) {
        const float* p = wbase + (size_t)(kt * 64 + 2 * kp) * NN;
        a = *(const float4*)(p);
        b = *(const float4*)(p + NN);
        c = *(const float4*)(p + 32 * NN);
        d = *(const float4*)(p + 33 * NN);
    };
    auto loadX = [&](int kt, uintx4& h0, uintx4& h1, uintx4& l0, uintx4& l1) {
        h0 = *(const uintx4*)(xhb + kt * 64);
        h1 = *(const uintx4*)(xhb + kt * 64 + 8);
        l0 = *(const uintx4*)(xlb + kt * 64);
        l1 = *(const uintx4*)(xlb + kt * 64 + 8);
    };
    auto stageW = [&](const float4& a, const float4& b, const float4& c, const float4& d) {
        const float* a0 = (const float*)&a;   // k = 2kp
        const float* a1 = (const float*)&b;   // k = 2kp+1
        const float* a2 = (const float*)&c;   // k = 2kp+32
        const float* a3 = (const float*)&d;   // k = 2kp+33
        #pragma unroll
        for (int j = 0; j < 4; ++j) {
            int n = no * 4 + j;
            unsigned h, l;
            splitpk(a0[j], a1[j], h, l);
            *(unsigned*)&WTh[n][2*kp] = h;
            *(unsigned*)&WTl[n][2*kp] = l;
            splitpk(a2[j], a3[j], h, l);
            *(unsigned*)&WTh[n][2*kp + 32] = h;
            *(unsigned*)&WTl[n][2*kp + 32] = l;
        }
    };
    auto stageX = [&](uintx4 h0, uintx4 h1, uintx4 l0, uintx4 l1) {
        *(uintx4*)&XSh[xr][xc*16]     = h0;
        *(uintx4*)&XSh[xr][xc*16 + 8] = h1;
        *(uintx4*)&XSl[xr][xc*16]     = l0;
        *(uintx4*)&XSl[xr][xc*16 + 8] = l1;
    };

#define MFMA_PHASE()                                                           \
    {                                                                          \
        _Pragma("unroll")                                                      \
        for (int ks = 0; ks < 2; ++ks) {                                       \
            const int kk = ks * 32 + (lane >> 4) * 8;                          \
            const int ln = lane & 15;                                          \
            bf16x8 Bh0 = *(const bf16x8*)&WTh[wn + ln][kk];                    \
            bf16x8 Bl0 = *(const bf16x8*)&WTl[wn + ln][kk];                    \
            bf16x8 Bh1 = *(const bf16x8*)&WTh[wn + 16 + ln][kk];               \
            bf16x8 Bl1 = *(const bf16x8*)&WTl[wn + 16 + ln][kk];               \
            bf16x8 Ah0 = *(const bf16x8*)&XSh[wm + ln][kk];                    \
            bf16x8 Al0 = *(const bf16x8*)&XSl[wm + ln][kk];                    \
            bf16x8 Ah1 = *(const bf16x8*)&XSh[wm + 16 + ln][kk];               \
            bf16x8 Al1 = *(const bf16x8*)&XSl[wm + 16 + ln][kk];               \
            acc00 = __builtin_amdgcn_mfma_f32_16x16x32_bf16(Ah0, Bh0, acc00, 0, 0, 0); \
            acc00 = __builtin_amdgcn_mfma_f32_16x16x32_bf16(Ah0, Bl0, acc00, 0, 0, 0); \
            acc00 = __builtin_amdgcn_mfma_f32_16x16x32_bf16(Al0, Bh0, acc00, 0, 0, 0); \
            acc01 = __builtin_amdgcn_mfma_f32_16x16x32_bf16(Ah0, Bh1, acc01, 0, 0, 0); \
            acc01 = __builtin_amdgcn_mfma_f32_16x16x32_bf16(Ah0, Bl1, acc01, 0, 0, 0); \
            acc01 = __builtin_amdgcn_mfma_f32_16x16x32_bf16(Al0, Bh1, acc01, 0, 0, 0); \
            acc10 = __builtin_amdgcn_mfma_f32_16x16x32_bf16(Ah1, Bh0, acc10, 0, 0, 0); \
            acc10 = __builtin_amdgcn_mfma_f32_16x16x32_bf16(Ah1, Bl0, acc10, 0, 0, 0); \
            acc10 = __builtin_amdgcn_mfma_f32_16x16x32_bf16(Al1, Bh0, acc10, 0, 0, 0); \
            acc11 = __builtin_amdgcn_mfma_f32_16x16x32_bf16(Ah1, Bh1, acc11, 0, 0, 0); \
            acc11 = __builtin_amdgcn_mfma_f32_16x16x32_bf16(Ah1, Bl1, acc11, 0, 0, 0); \
            acc11 = __builtin_amdgcn_mfma_f32_16x16x32_bf16(Al1, Bh1, acc11, 0, 0, 0); \
        }                                                                      \
    }

    float4 wa0, wa1, wa2, wa3, wb0, wb1, wb2, wb3;
    uintx4 xa0, xa1, xa2, xa3, xb0, xb1, xb2, xb3;
    const int nkt = kchunk >> 6;             // 32 (fc1) or 2 (fc2), even
    loadW(0, wa0, wa1, wa2, wa3);
    loadW(1, wb0, wb1, wb2, wb3);
    loadX(0, xa0, xa1, xa2, xa3);

    for (int ktp = 0; ktp < nkt; ktp += 2) {
        // ---- even sub-iteration: tile ktp
        __syncthreads();
        stageW(wa0, wa1, wa2, wa3);
        stageX(xa0, xa1, xa2, xa3);
        loadX(ktp + 1, xb0, xb1, xb2, xb3);
        if (ktp + 2 < nkt) loadW(ktp + 2, wa0, wa1, wa2, wa3);
        __syncthreads();
        MFMA_PHASE();
        // ---- odd sub-iteration: tile ktp+1
        __syncthreads();
        stageW(wb0, wb1, wb2, wb3);
        stageX(xb0, xb1, xb2, xb3);
        if (ktp + 3 < nkt) loadW(ktp + 3, wb0, wb1, wb2, wb3);
        if (ktp + 2 < nkt) loadX(ktp + 2, xa0, xa1, xa2, xa3);
        __syncthreads();
        MFMA_PHASE();
    }
#undef MFMA_PHASE

    // ---- write partials: D row = (lane>>4)*4 + i, col = lane&15
    const int ln  = lane & 15;
    const int orb = (lane >> 4) * 4;
    #pragma unroll
    for (int i = 0; i < 4; ++i) {
        int m0r = wm + orb + i, m1r = wm + 16 + orb + i;
        size_t base0 = ((size_t)kc * MM + m0r) * NN + n0 + wn + ln;
        size_t base1 = ((size_t)kc * MM + m1r) * NN + n0 + wn + ln;
        P[base0]      = acc00[i];
        P[base0 + 16] = acc01[i];
        P[base1]      = acc10[i];
        P[base1 + 16] = acc11[i];
    }
}

// ---------------- Stage 3a: reduce partials + bias + relu -> bf16 hi/lo -----
__global__ void reduce_bias_split(const float* __restrict__ P,
                                  const float* __restrict__ bias,
                                  unsigned short* __restrict__ Yhi,
                                  unsigned short* __restrict__ Ylo, int KC) {
    int idx = blockIdx.x * 256 + threadIdx.x;   // 0..65535
    int n = idx & (NN - 1);
    float s = bias[n];
    for (int kc = 0; kc < KC; ++kc) s += P[(size_t)kc * (MM*NN) + idx];
    s = fmaxf(s, 0.f);
    unsigned short h = f2bf(s);
    Yhi[idx] = h;
    Ylo[idx] = f2bf(s - bf2f(h));
}

// ---------------- Stage 3b: reduce partials + bias + relu -> fp32 -----------
__global__ void reduce_bias_relu(const float* __restrict__ P,
                                 const float* __restrict__ bias,
                                 float* __restrict__ Y, int KC) {
    int idx = blockIdx.x * 256 + threadIdx.x;
    int n = idx & (NN - 1);
    float s = bias[n];
    for (int kc = 0; kc < KC; ++kc) s += P[(size_t)kc * (MM*NN) + idx];
    Y[idx] = fmaxf(s, 0.f);
}

// ---------------- Stage 4: heads --------------------------------------------
__global__ void heads_kernel(const float* __restrict__ h2,
                             const float* __restrict__ Wc, const float* __restrict__ bc,
                             const float* __restrict__ Wb, const float* __restrict__ bb,
                             float* __restrict__ out) {
    int m = blockIdx.x;
    int t = threadIdx.x;   // 256
    float a[6] = {0,0,0,0,0,0};
    for (int k = t; k < 1024; k += 256) {
        float xv = h2[(size_t)m * 1024 + k];
        a[0] += xv * Wc[k*2 + 0];
        a[1] += xv * Wc[k*2 + 1];
        a[2] += xv * Wb[k*4 + 0];
        a[3] += xv * Wb[k*4 + 1];
        a[4] += xv * Wb[k*4 + 2];
        a[5] += xv * Wb[k*4 + 3];
    }
    __shared__ float red[6][256];
    #pragma unroll
    for (int j = 0; j < 6; ++j) red[j][t] = a[j];
    __syncthreads();
    for (int s = 128; s > 0; s >>= 1) {
        if (t < s) {
            #pragma unroll
            for (int j = 0; j < 6; ++j) red[j][t] += red[j][t + s];
        }
        __syncthreads();
    }
    if (t == 0) {
        float l0 = red[0][0] + bc[0], l1 = red[1][0] + bc[1];
        float mx = fmaxf(l0, l1);
        float e0 = expf(l0 - mx), e1 = expf(l1 - mx);
        float inv = 1.f / (e0 + e1);
        out[m*2 + 0] = e0 * inv;
        out[m*2 + 1] = e1 * inv;
        out[128 + m*4 + 0] = red[2][0] + bb[0];
        out[128 + m*4 + 1] = red[3][0] + bb[1];
        out[128 + m*4 + 2] = red[4][0] + bb[2];
        out[128 + m*4 + 3] = red[5][0] + bb[3];
    }
}

extern "C" void kernel_launch(void* const* d_in, const int* in_sizes, int n_in,
                              void* d_out, int out_size, void* d_ws, size_t ws_size,
                              hipStream_t stream) {
    const float* fm    = (const float*)d_in[0];
    const float* boxes = (const float*)d_in[1];
    const float* W1    = (const float*)d_in[2];
    const float* b1    = (const float*)d_in[3];
    const float* W2    = (const float*)d_in[4];
    const float* b2    = (const float*)d_in[5];
    const float* Wc    = (const float*)d_in[6];
    const float* bc    = (const float*)d_in[7];
    const float* Wb    = (const float*)d_in[8];
    const float* bb    = (const float*)d_in[9];
    float* out = (float*)d_out;
    char* ws = (char*)d_ws;

    const size_t XB = (size_t)NROIS * DD * sizeof(unsigned short);  // 12,845,056
    unsigned short* Xhi  = (unsigned short*)ws;
    unsigned short* Xlo  = (unsigned short*)(ws + XB);
    float*          P1   = (float*)(ws + 2 * XB);                   // 12,845,056 B
    unsigned short* h1hi = (unsigned short*)(ws + 3 * XB);          // 131,072 B
    unsigned short* h1lo = (unsigned short*)(ws + 3 * XB + 131072);
    float*          P2   = (float*)(ws + 3 * XB + 262144);          // 2,097,152 B
    float*          h2   = (float*)(ws + 3 * XB + 262144 + 2097152);

    crop_kernel<<<dim3(NROIS, SS*SS), 512, 0, stream>>>(fm, boxes, Xhi, Xlo);
    fc_mfma<<<dim3(16, KC1), 256, 0, stream>>>(Xhi, Xlo, W1, P1, DD, 2048);
    reduce_bias_split<<<(MM*NN)/256, 256, 0, stream>>>(P1, b1, h1hi, h1lo, KC1);
    fc_mfma<<<dim3(16, 8), 256, 0, stream>>>(h1hi, h1lo, W2, P2, NN, 128);
    reduce_bias_relu<<<(MM*NN)/256, 256, 0, stream>>>(P2, b2, h2, 8);
    heads_kernel<<<NROIS, 256, 0, stream>>>(h2, Wc, bc, Wb, bb, out);
}

// Round 5
// 231.010 us; speedup vs baseline: 1.4788x; 1.0010x over previous
//
#include <hip/hip_runtime.h>
#include <math.h>

#define SS 7
#define NROIS 64
#define CC 2048
#define DD (SS*SS*CC)   // 100352
#define MM 64
#define NN 1024
#define KC1 49          // 49*2048 = 100352

typedef float f32x4 __attribute__((ext_vector_type(4)));
typedef __bf16 bf16x8 __attribute__((ext_vector_type(8)));

__device__ __forceinline__ unsigned short f2bf(float f){
    unsigned u = __builtin_bit_cast(unsigned, f);
    u += 0x7fffu + ((u >> 16) & 1u);           // RNE
    return (unsigned short)(u >> 16);
}
__device__ __forceinline__ float bf2f(unsigned short h){
    unsigned u = ((unsigned)h) << 16;
    return __builtin_bit_cast(float, u);
}
__device__ __forceinline__ void splitpk(float v0, float v1, unsigned& h, unsigned& l){
    __bf16 h0 = (__bf16)v0, h1 = (__bf16)v1;
    float r0 = v0 - (float)h0, r1 = v1 - (float)h1;
    __bf16 l0 = (__bf16)r0, l1 = (__bf16)r1;
    h = (unsigned)__builtin_bit_cast(unsigned short, h0) |
        ((unsigned)__builtin_bit_cast(unsigned short, h1) << 16);
    l = (unsigned)__builtin_bit_cast(unsigned short, l0) |
        ((unsigned)__builtin_bit_cast(unsigned short, l1) << 16);
}

// ---------------- Stage 1: crop + bilinear resize -> bf16 hi/lo planes ------
__global__ void crop_kernel(const float* __restrict__ fm,
                            const float* __restrict__ boxes,
                            unsigned short* __restrict__ Xhi,
                            unsigned short* __restrict__ Xlo) {
    int roi = blockIdx.x;
    int p   = blockIdx.y;         // 0..48
    int sy = p / SS, sx = p % SS;
    const float* b = boxes + roi * 4;
    float x1 = fmaxf(0.f, rintf(b[0]));
    float y1 = fmaxf(0.f, rintf(b[1]));
    float x2 = fminf(15.f, rintf(b[2]));
    float y2 = fminf(15.f, rintf(b[3]));
    float h = y2 - y1, w = x2 - x1;
    float iy = ((sy + 0.5f) * h) / 7.0f - 0.5f;
    float ix = ((sx + 0.5f) * w) / 7.0f - 0.5f;
    iy = fminf(fmaxf(iy, 0.f), h - 1.f);
    ix = fminf(fmaxf(ix, 0.f), w - 1.f);
    float y0 = floorf(iy), x0 = floorf(ix);
    float fy = iy - y0,   fx = ix - x0;
    int y0i = (int)(y1 + y0);
    int y1i = min(y0i + 1, (int)(y1 + h - 1.f));
    int x0i = (int)(x1 + x0);
    int x1i = min(x0i + 1, (int)(x1 + w - 1.f));

    int c = threadIdx.x * 4;
    const float4 v00 = *(const float4*)(fm + ((size_t)(y0i*16 + x0i))*CC + c);
    const float4 v01 = *(const float4*)(fm + ((size_t)(y0i*16 + x1i))*CC + c);
    const float4 v10 = *(const float4*)(fm + ((size_t)(y1i*16 + x0i))*CC + c);
    const float4 v11 = *(const float4*)(fm + ((size_t)(y1i*16 + x1i))*CC + c);
    float gy = 1.f - fy, gx = 1.f - fx;
    float o[4];
    o[0] = (v00.x*gy + v10.x*fy)*gx + (v01.x*gy + v11.x*fy)*fx;
    o[1] = (v00.y*gy + v10.y*fy)*gx + (v01.y*gy + v11.y*fy)*fx;
    o[2] = (v00.z*gy + v10.z*fy)*gx + (v01.z*gy + v11.z*fy)*fx;
    o[3] = (v00.w*gy + v10.w*fy)*gx + (v01.w*gy + v11.w*fy)*fx;
    uint2 hv, lv;
    splitpk(o[0], o[1], hv.x, lv.x);
    splitpk(o[2], o[3], hv.y, lv.y);
    size_t off = (size_t)roi*DD + (size_t)p*CC + c;
    *(uint2*)(Xhi + off) = hv;
    *(uint2*)(Xlo + off) = lv;
}

// ---------------- Stage 2: generic FC via bf16x2-split MFMA -----------------
// grid (n-tiles of 64, k-chunks), 256 thr = 4 waves in 2x2 (32m x 32n each).
// W (fp32) staged through LDS (transposed, hi/lo split), 2-deep reg prefetch.
// A (bf16 hi/lo planes) loaded per-lane DIRECT to registers, 2-deep prefetch
// (pattern verified in round 3). 3-term: D += Ah*Bh + Ah*Bl + Al*Bh.
__global__ __launch_bounds__(256, 3)
void fc_mfma(const unsigned short* __restrict__ Ahi,
             const unsigned short* __restrict__ Alo,
             const float* __restrict__ Wm, float* __restrict__ P,
             int astride, int kchunk) {
    const int nb = blockIdx.x, kc = blockIdx.y;
    const int n0 = nb * 64;
    const int k0 = kc * kchunk;
    const int t = threadIdx.x;
    const int lane = t & 63, wv = t >> 6;
    const int ln = lane & 15;
    const int wm = (wv & 1) * 32;            // wave m-half
    const int wn = (wv >> 1) * 32;           // wave n-half
    const int kp = t & 15, no = t >> 4;      // W staging: k-pair, n-quad

    __shared__ unsigned short WTh[64][72];   // [n][k] transposed, hi
    __shared__ unsigned short WTl[64][72];   // lo

    f32x4 acc00 = {0,0,0,0}, acc01 = {0,0,0,0};
    f32x4 acc10 = {0,0,0,0}, acc11 = {0,0,0,0};

    // A fragment bases: rows wm+ln and wm+16+ln, k-offset (lane>>4)*8
    const int koff = (lane >> 4) * 8;
    const unsigned short* a0hb = Ahi + (size_t)(wm + ln) * astride + k0 + koff;
    const unsigned short* a1hb = Ahi + (size_t)(wm + 16 + ln) * astride + k0 + koff;
    const unsigned short* a0lb = Alo + (size_t)(wm + ln) * astride + k0 + koff;
    const unsigned short* a1lb = Alo + (size_t)(wm + 16 + ln) * astride + k0 + koff;

    const float* wbase = Wm + (size_t)k0 * NN + n0 + no * 4;

    auto loadW = [&](int kt, float4& a, float4& b, float4& c, float4& d) {
        const float* p = wbase + (size_t)(kt * 64 + 2 * kp) * NN;
        a = *(const float4*)(p);
        b = *(const float4*)(p + NN);
        c = *(const float4*)(p + 32 * NN);
        d = *(const float4*)(p + 33 * NN);
    };
    // A regs per kt: [row0/row1] x [ks0/ks1] x [hi/lo] = 8 x 16B
    auto loadA = [&](int kt, bf16x8& h00, bf16x8& h01, bf16x8& h10, bf16x8& h11,
                             bf16x8& l00, bf16x8& l01, bf16x8& l10, bf16x8& l11) {
        h00 = *(const bf16x8*)(a0hb + kt * 64);
        h01 = *(const bf16x8*)(a0hb + kt * 64 + 32);
        h10 = *(const bf16x8*)(a1hb + kt * 64);
        h11 = *(const bf16x8*)(a1hb + kt * 64 + 32);
        l00 = *(const bf16x8*)(a0lb + kt * 64);
        l01 = *(const bf16x8*)(a0lb + kt * 64 + 32);
        l10 = *(const bf16x8*)(a1lb + kt * 64);
        l11 = *(const bf16x8*)(a1lb + kt * 64 + 32);
    };
    auto stageW = [&](const float4& a, const float4& b, const float4& c, const float4& d) {
        const float* a0 = (const float*)&a;   // k = 2kp
        const float* a1 = (const float*)&b;   // k = 2kp+1
        const float* a2 = (const float*)&c;   // k = 2kp+32
        const float* a3 = (const float*)&d;   // k = 2kp+33
        #pragma unroll
        for (int j = 0; j < 4; ++j) {
            int n = no * 4 + j;
            unsigned h, l;
            splitpk(a0[j], a1[j], h, l);
            *(unsigned*)&WTh[n][2*kp] = h;
            *(unsigned*)&WTl[n][2*kp] = l;
            splitpk(a2[j], a3[j], h, l);
            *(unsigned*)&WTh[n][2*kp + 32] = h;
            *(unsigned*)&WTl[n][2*kp + 32] = l;
        }
    };

    // MFMA phase for one kt: B frags from LDS, A frags from the given regs.
#define MFMA_PHASE(H00,H01,H10,H11,L00,L01,L10,L11)                            \
    {                                                                          \
        _Pragma("unroll")                                                      \
        for (int ks = 0; ks < 2; ++ks) {                                       \
            const int kk = ks * 32 + koff;                                     \
            bf16x8 Bh0 = *(const bf16x8*)&WTh[wn + ln][kk];                    \
            bf16x8 Bl0 = *(const bf16x8*)&WTl[wn + ln][kk];                    \
            bf16x8 Bh1 = *(const bf16x8*)&WTh[wn + 16 + ln][kk];               \
            bf16x8 Bl1 = *(const bf16x8*)&WTl[wn + 16 + ln][kk];               \
            bf16x8 Ah0 = ks ? H01 : H00;                                       \
            bf16x8 Al0 = ks ? L01 : L00;                                       \
            bf16x8 Ah1 = ks ? H11 : H10;                                       \
            bf16x8 Al1 = ks ? L11 : L10;                                       \
            acc00 = __builtin_amdgcn_mfma_f32_16x16x32_bf16(Ah0, Bh0, acc00, 0, 0, 0); \
            acc00 = __builtin_amdgcn_mfma_f32_16x16x32_bf16(Ah0, Bl0, acc00, 0, 0, 0); \
            acc00 = __builtin_amdgcn_mfma_f32_16x16x32_bf16(Al0, Bh0, acc00, 0, 0, 0); \
            acc01 = __builtin_amdgcn_mfma_f32_16x16x32_bf16(Ah0, Bh1, acc01, 0, 0, 0); \
            acc01 = __builtin_amdgcn_mfma_f32_16x16x32_bf16(Ah0, Bl1, acc01, 0, 0, 0); \
            acc01 = __builtin_amdgcn_mfma_f32_16x16x32_bf16(Al0, Bh1, acc01, 0, 0, 0); \
            acc10 = __builtin_amdgcn_mfma_f32_16x16x32_bf16(Ah1, Bh0, acc10, 0, 0, 0); \
            acc10 = __builtin_amdgcn_mfma_f32_16x16x32_bf16(Ah1, Bl0, acc10, 0, 0, 0); \
            acc10 = __builtin_amdgcn_mfma_f32_16x16x32_bf16(Al1, Bh0, acc10, 0, 0, 0); \
            acc11 = __builtin_amdgcn_mfma_f32_16x16x32_bf16(Ah1, Bh1, acc11, 0, 0, 0); \
            acc11 = __builtin_amdgcn_mfma_f32_16x16x32_bf16(Ah1, Bl1, acc11, 0, 0, 0); \
            acc11 = __builtin_amdgcn_mfma_f32_16x16x32_bf16(Al1, Bh1, acc11, 0, 0, 0); \
        }                                                                      \
    }

    float4 wa0, wa1, wa2, wa3, wb0, wb1, wb2, wb3;
    bf16x8 Aa0,Aa1,Aa2,Aa3, Aa4,Aa5,Aa6,Aa7;   // set A (even kt)
    bf16x8 Ab0,Ab1,Ab2,Ab3, Ab4,Ab5,Ab6,Ab7;   // set B (odd kt)
    const int nkt = kchunk >> 6;               // 32 (fc1) or 2 (fc2), even
    loadW(0, wa0, wa1, wa2, wa3);
    loadW(1, wb0, wb1, wb2, wb3);
    loadA(0, Aa0,Aa1,Aa2,Aa3, Aa4,Aa5,Aa6,Aa7);
    loadA(1, Ab0,Ab1,Ab2,Ab3, Ab4,Ab5,Ab6,Ab7);

    for (int ktp = 0; ktp < nkt; ktp += 2) {
        // ---- even sub-iteration: tile ktp
        __syncthreads();
        stageW(wa0, wa1, wa2, wa3);
        if (ktp + 2 < nkt) loadW(ktp + 2, wa0, wa1, wa2, wa3);
        __syncthreads();
        MFMA_PHASE(Aa0,Aa1,Aa2,Aa3, Aa4,Aa5,Aa6,Aa7);
        if (ktp + 2 < nkt) loadA(ktp + 2, Aa0,Aa1,Aa2,Aa3, Aa4,Aa5,Aa6,Aa7);
        // ---- odd sub-iteration: tile ktp+1
        __syncthreads();
        stageW(wb0, wb1, wb2, wb3);
        if (ktp + 3 < nkt) loadW(ktp + 3, wb0, wb1, wb2, wb3);
        __syncthreads();
        MFMA_PHASE(Ab0,Ab1,Ab2,Ab3, Ab4,Ab5,Ab6,Ab7);
        if (ktp + 3 < nkt) loadA(ktp + 3, Ab0,Ab1,Ab2,Ab3, Ab4,Ab5,Ab6,Ab7);
    }
#undef MFMA_PHASE

    // ---- write partials: D row = (lane>>4)*4 + i, col = lane&15
    const int orb = (lane >> 4) * 4;
    #pragma unroll
    for (int i = 0; i < 4; ++i) {
        int m0r = wm + orb + i, m1r = wm + 16 + orb + i;
        size_t base0 = ((size_t)kc * MM + m0r) * NN + n0 + wn + ln;
        size_t base1 = ((size_t)kc * MM + m1r) * NN + n0 + wn + ln;
        P[base0]      = acc00[i];
        P[base0 + 16] = acc01[i];
        P[base1]      = acc10[i];
        P[base1 + 16] = acc11[i];
    }
}

// ---------------- Stage 3: reduce partials + bias + relu -> bf16 hi/lo ------
__global__ void reduce_bias_split(const float* __restrict__ P,
                                  const float* __restrict__ bias,
                                  unsigned short* __restrict__ Yhi,
                                  unsigned short* __restrict__ Ylo, int KC) {
    int idx = blockIdx.x * 256 + threadIdx.x;   // 0..65535
    int n = idx & (NN - 1);
    float s = bias[n];
    for (int kc = 0; kc < KC; ++kc) s += P[(size_t)kc * (MM*NN) + idx];
    s = fmaxf(s, 0.f);
    unsigned short h = f2bf(s);
    Yhi[idx] = h;
    Ylo[idx] = f2bf(s - bf2f(h));
}

// ---------------- Stage 4: fused P2-reduce + bias + relu + heads ------------
__global__ void heads_kernel(const float* __restrict__ P2,
                             const float* __restrict__ b2,
                             const float* __restrict__ Wc, const float* __restrict__ bc,
                             const float* __restrict__ Wb, const float* __restrict__ bb,
                             float* __restrict__ out) {
    int m = blockIdx.x;
    int t = threadIdx.x;   // 256
    float a[6] = {0,0,0,0,0,0};
    #pragma unroll
    for (int j = 0; j < 4; ++j) {
        int n = j * 256 + t;
        float s = b2[n];
        #pragma unroll
        for (int kc = 0; kc < 8; ++kc)
            s += P2[((size_t)kc * MM + m) * NN + n];
        s = fmaxf(s, 0.f);
        a[0] += s * Wc[n*2 + 0];
        a[1] += s * Wc[n*2 + 1];
        a[2] += s * Wb[n*4 + 0];
        a[3] += s * Wb[n*4 + 1];
        a[4] += s * Wb[n*4 + 2];
        a[5] += s * Wb[n*4 + 3];
    }
    __shared__ float red[6][256];
    #pragma unroll
    for (int j = 0; j < 6; ++j) red[j][t] = a[j];
    __syncthreads();
    for (int s = 128; s > 0; s >>= 1) {
        if (t < s) {
            #pragma unroll
            for (int j = 0; j < 6; ++j) red[j][t] += red[j][t + s];
        }
        __syncthreads();
    }
    if (t == 0) {
        float l0 = red[0][0] + bc[0], l1 = red[1][0] + bc[1];
        float mx = fmaxf(l0, l1);
        float e0 = expf(l0 - mx), e1 = expf(l1 - mx);
        float inv = 1.f / (e0 + e1);
        out[m*2 + 0] = e0 * inv;
        out[m*2 + 1] = e1 * inv;
        out[128 + m*4 + 0] = red[2][0] + bb[0];
        out[128 + m*4 + 1] = red[3][0] + bb[1];
        out[128 + m*4 + 2] = red[4][0] + bb[2];
        out[128 + m*4 + 3] = red[5][0] + bb[3];
    }
}

extern "C" void kernel_launch(void* const* d_in, const int* in_sizes, int n_in,
                              void* d_out, int out_size, void* d_ws, size_t ws_size,
                              hipStream_t stream) {
    const float* fm    = (const float*)d_in[0];
    const float* boxes = (const float*)d_in[1];
    const float* W1    = (const float*)d_in[2];
    const float* b1    = (const float*)d_in[3];
    const float* W2    = (const float*)d_in[4];
    const float* b2    = (const float*)d_in[5];
    const float* Wc    = (const float*)d_in[6];
    const float* bc    = (const float*)d_in[7];
    const float* Wb    = (const float*)d_in[8];
    const float* bb    = (const float*)d_in[9];
    float* out = (float*)d_out;
    char* ws = (char*)d_ws;

    const size_t XB = (size_t)NROIS * DD * sizeof(unsigned short);  // 12,845,056
    unsigned short* Xhi  = (unsigned short*)ws;
    unsigned short* Xlo  = (unsigned short*)(ws + XB);
    float*          P1   = (float*)(ws + 2 * XB);                   // 12,845,056 B
    unsigned short* h1hi = (unsigned short*)(ws + 3 * XB);          // 131,072 B
    unsigned short* h1lo = (unsigned short*)(ws + 3 * XB + 131072);
    float*          P2   = (float*)(ws + 3 * XB + 262144);          // 2,097,152 B

    crop_kernel<<<dim3(NROIS, SS*SS), 512, 0, stream>>>(fm, boxes, Xhi, Xlo);
    fc_mfma<<<dim3(16, KC1), 256, 0, stream>>>(Xhi, Xlo, W1, P1, DD, 2048);
    reduce_bias_split<<<(MM*NN)/256, 256, 0, stream>>>(P1, b1, h1hi, h1lo, KC1);
    fc_mfma<<<dim3(16, 8), 256, 0, stream>>>(h1hi, h1lo, W2, P2, NN, 128);
    heads_kernel<<<NROIS, 256, 0, stream>>>(P2, b2, Wc, bc, Wb, bb, out);
}

// Round 6
// 212.695 us; speedup vs baseline: 1.6061x; 1.0861x over previous
//
#include <hip/hip_runtime.h>
#include <math.h>

#define SS 7
#define NROIS 64
#define CC 2048
#define DD (SS*SS*CC)   // 100352
#define MM 64
#define NN 1024
#define KC1 98          // k-chunks for fc1 (KCH=1024)
#define KC2 16          // k-chunks for fc2 (KCH=64)

typedef float f32x4 __attribute__((ext_vector_type(4)));
typedef __bf16 bf16x8 __attribute__((ext_vector_type(8)));

__device__ __forceinline__ unsigned short f2bf(float f){
    unsigned u = __builtin_bit_cast(unsigned, f);
    u += 0x7fffu + ((u >> 16) & 1u);           // RNE
    return (unsigned short)(u >> 16);
}
__device__ __forceinline__ float bf2f(unsigned short h){
    unsigned u = ((unsigned)h) << 16;
    return __builtin_bit_cast(float, u);
}
__device__ __forceinline__ void splitpk(float v0, float v1, unsigned& h, unsigned& l){
    __bf16 h0 = (__bf16)v0, h1 = (__bf16)v1;
    float r0 = v0 - (float)h0, r1 = v1 - (float)h1;
    __bf16 l0 = (__bf16)r0, l1 = (__bf16)r1;
    h = (unsigned)__builtin_bit_cast(unsigned short, h0) |
        ((unsigned)__builtin_bit_cast(unsigned short, h1) << 16);
    l = (unsigned)__builtin_bit_cast(unsigned short, l0) |
        ((unsigned)__builtin_bit_cast(unsigned short, l1) << 16);
}

// ---------------- Stage 1: crop + bilinear resize -> bf16 hi/lo planes ------
__global__ void crop_kernel(const float* __restrict__ fm,
                            const float* __restrict__ boxes,
                            unsigned short* __restrict__ Xhi,
                            unsigned short* __restrict__ Xlo) {
    int roi = blockIdx.x;
    int p   = blockIdx.y;         // 0..48
    int sy = p / SS, sx = p % SS;
    const float* b = boxes + roi * 4;
    float x1 = fmaxf(0.f, rintf(b[0]));
    float y1 = fmaxf(0.f, rintf(b[1]));
    float x2 = fminf(15.f, rintf(b[2]));
    float y2 = fminf(15.f, rintf(b[3]));
    float h = y2 - y1, w = x2 - x1;
    float iy = ((sy + 0.5f) * h) / 7.0f - 0.5f;
    float ix = ((sx + 0.5f) * w) / 7.0f - 0.5f;
    iy = fminf(fmaxf(iy, 0.f), h - 1.f);
    ix = fminf(fmaxf(ix, 0.f), w - 1.f);
    float y0 = floorf(iy), x0 = floorf(ix);
    float fy = iy - y0,   fx = ix - x0;
    int y0i = (int)(y1 + y0);
    int y1i = min(y0i + 1, (int)(y1 + h - 1.f));
    int x0i = (int)(x1 + x0);
    int x1i = min(x0i + 1, (int)(x1 + w - 1.f));

    int c = threadIdx.x * 4;
    const float4 v00 = *(const float4*)(fm + ((size_t)(y0i*16 + x0i))*CC + c);
    const float4 v01 = *(const float4*)(fm + ((size_t)(y0i*16 + x1i))*CC + c);
    const float4 v10 = *(const float4*)(fm + ((size_t)(y1i*16 + x0i))*CC + c);
    const float4 v11 = *(const float4*)(fm + ((size_t)(y1i*16 + x1i))*CC + c);
    float gy = 1.f - fy, gx = 1.f - fx;
    float o[4];
    o[0] = (v00.x*gy + v10.x*fy)*gx + (v01.x*gy + v11.x*fy)*fx;
    o[1] = (v00.y*gy + v10.y*fy)*gx + (v01.y*gy + v11.y*fy)*fx;
    o[2] = (v00.z*gy + v10.z*fy)*gx + (v01.z*gy + v11.z*fy)*fx;
    o[3] = (v00.w*gy + v10.w*fy)*gx + (v01.w*gy + v11.w*fy)*fx;
    uint2 hv, lv;
    splitpk(o[0], o[1], hv.x, lv.x);
    splitpk(o[2], o[3], hv.y, lv.y);
    size_t off = (size_t)roi*DD + (size_t)p*CC + c;
    *(uint2*)(Xhi + off) = hv;
    *(uint2*)(Xlo + off) = lv;
}

// ---------------- Stage 2: generic FC via bf16x2-split MFMA -----------------
// grid (4 n-tiles of 256, k-chunks). Block 64m x 256n, BK=32.
// Each block reads W rows in 1 KB contiguous chunks (vs 256 B before) --
// HBM granularity fix. 4 waves each 64m x 64n (16 frags, 48 MFMA/kt).
// W: reg->LDS transposed bf16 hi/lo (2-deep prefetch); A: reg double-buffer.
// 3-term: D += Ah*Bh + Ah*Bl + Al*Bh.
__global__ __launch_bounds__(256, 2)
void fc_mfma(const unsigned short* __restrict__ Ahi,
             const unsigned short* __restrict__ Alo,
             const float* __restrict__ Wm, float* __restrict__ P,
             int astride, int kchunk) {
    const int nb = blockIdx.x, kc = blockIdx.y;
    const int n0 = nb * 256;
    const int k0 = kc * kchunk;
    const int t = threadIdx.x;
    const int lane = t & 63, wv = t >> 6;
    const int ln = lane & 15;
    const int koff = (lane >> 4) * 8;        // k-offset within BK=32
    const int kp = t & 15, no = t >> 4;      // staging: k-pair, n-group of 16

    __shared__ unsigned short WTh[256][34];  // [n][k] transposed, hi (pad->2-way max)
    __shared__ unsigned short WTl[256][34];  // lo

    f32x4 acc[16];                           // [nf*4+mf], static idx only
    #pragma unroll
    for (int i = 0; i < 16; ++i) acc[i] = (f32x4){0.f, 0.f, 0.f, 0.f};

    // A fragment row offsets (rows mf*16+ln of the 64-roi matrix)
    size_t arow[4];
    #pragma unroll
    for (int mf = 0; mf < 4; ++mf)
        arow[mf] = (size_t)(mf * 16 + ln) * astride;

    const float* wbase = Wm + (size_t)k0 * NN + n0 + no * 16;

    float4 wa[8], wb[8];                     // 2-deep W prefetch (32 regs each)
    bf16x8 Aah[4], Aal[4], Abh[4], Abl[4];   // A double buffer

    auto loadW = [&](int kt, float4* r) {
        const float* p = wbase + (size_t)(kt * 32 + 2 * kp) * NN;
        #pragma unroll
        for (int j = 0; j < 4; ++j) {
            r[j]     = *(const float4*)(p + j * 4);        // row 2kp
            r[j + 4] = *(const float4*)(p + NN + j * 4);   // row 2kp+1
        }
    };
    auto loadA = [&](int kt, bf16x8* Ah, bf16x8* Al) {
        const size_t kk = (size_t)k0 + kt * 32 + koff;
        #pragma unroll
        for (int mf = 0; mf < 4; ++mf) {
            Ah[mf] = *(const bf16x8*)(Ahi + arow[mf] + kk);
            Al[mf] = *(const bf16x8*)(Alo + arow[mf] + kk);
        }
    };
    auto stageW = [&](const float4* r) {
        #pragma unroll
        for (int j = 0; j < 4; ++j) {
            #pragma unroll
            for (int e = 0; e < 4; ++e) {
                int n = no * 16 + j * 4 + e;
                unsigned h, l;
                splitpk(((const float*)&r[j])[e], ((const float*)&r[j + 4])[e], h, l);
                *(unsigned*)&WTh[n][2 * kp] = h;
                *(unsigned*)&WTl[n][2 * kp] = l;
            }
        }
    };

#define MFMA_PHASE(AH, AL)                                                     \
    {                                                                          \
        _Pragma("unroll")                                                      \
        for (int nf = 0; nf < 4; ++nf) {                                       \
            bf16x8 Bh = *(const bf16x8*)&WTh[wv * 64 + nf * 16 + ln][koff];    \
            bf16x8 Bl = *(const bf16x8*)&WTl[wv * 64 + nf * 16 + ln][koff];    \
            _Pragma("unroll")                                                  \
            for (int mf = 0; mf < 4; ++mf) {                                   \
                acc[nf*4+mf] = __builtin_amdgcn_mfma_f32_16x16x32_bf16(AH[mf], Bh, acc[nf*4+mf], 0, 0, 0); \
                acc[nf*4+mf] = __builtin_amdgcn_mfma_f32_16x16x32_bf16(AH[mf], Bl, acc[nf*4+mf], 0, 0, 0); \
                acc[nf*4+mf] = __builtin_amdgcn_mfma_f32_16x16x32_bf16(AL[mf], Bh, acc[nf*4+mf], 0, 0, 0); \
            }                                                                  \
        }                                                                      \
    }

    const int nkt = kchunk >> 5;             // BK=32: 32 (fc1) or 2 (fc2), even
    loadW(0, wa);
    loadW(1, wb);
    loadA(0, Aah, Aal);
    loadA(1, Abh, Abl);

    for (int ktp = 0; ktp < nkt; ktp += 2) {
        // ---- even tile ktp
        __syncthreads();
        stageW(wa);
        if (ktp + 2 < nkt) loadW(ktp + 2, wa);
        __syncthreads();
        MFMA_PHASE(Aah, Aal);
        if (ktp + 2 < nkt) loadA(ktp + 2, Aah, Aal);
        // ---- odd tile ktp+1
        __syncthreads();
        stageW(wb);
        if (ktp + 3 < nkt) loadW(ktp + 3, wb);
        __syncthreads();
        MFMA_PHASE(Abh, Abl);
        if (ktp + 3 < nkt) loadA(ktp + 3, Abh, Abl);
    }
#undef MFMA_PHASE

    // ---- write partials: D row = (lane>>4)*4 + i, col = lane&15 (verified r2)
    const int orb = (lane >> 4) * 4;
    #pragma unroll
    for (int nf = 0; nf < 4; ++nf) {
        int col = n0 + wv * 64 + nf * 16 + ln;
        #pragma unroll
        for (int mf = 0; mf < 4; ++mf) {
            #pragma unroll
            for (int i = 0; i < 4; ++i) {
                int m = mf * 16 + orb + i;
                P[((size_t)kc * MM + m) * NN + col] = acc[nf*4+mf][i];
            }
        }
    }
}

// ---------------- Stage 3: reduce partials + bias + relu -> bf16 hi/lo ------
__global__ void reduce_bias_split(const float* __restrict__ P,
                                  const float* __restrict__ bias,
                                  unsigned short* __restrict__ Yhi,
                                  unsigned short* __restrict__ Ylo, int KC) {
    int idx = blockIdx.x * 256 + threadIdx.x;   // 0..65535
    int n = idx & (NN - 1);
    float s = bias[n];
    for (int kc = 0; kc < KC; ++kc) s += P[(size_t)kc * (MM*NN) + idx];
    s = fmaxf(s, 0.f);
    unsigned short h = f2bf(s);
    Yhi[idx] = h;
    Ylo[idx] = f2bf(s - bf2f(h));
}

// ---------------- Stage 4: fused P2-reduce + bias + relu + heads ------------
__global__ void heads_kernel(const float* __restrict__ P2,
                             const float* __restrict__ b2,
                             const float* __restrict__ Wc, const float* __restrict__ bc,
                             const float* __restrict__ Wb, const float* __restrict__ bb,
                             float* __restrict__ out) {
    int m = blockIdx.x;
    int t = threadIdx.x;   // 256
    float a[6] = {0,0,0,0,0,0};
    #pragma unroll
    for (int j = 0; j < 4; ++j) {
        int n = j * 256 + t;
        float s = b2[n];
        #pragma unroll
        for (int kc = 0; kc < KC2; ++kc)
            s += P2[((size_t)kc * MM + m) * NN + n];
        s = fmaxf(s, 0.f);
        a[0] += s * Wc[n*2 + 0];
        a[1] += s * Wc[n*2 + 1];
        a[2] += s * Wb[n*4 + 0];
        a[3] += s * Wb[n*4 + 1];
        a[4] += s * Wb[n*4 + 2];
        a[5] += s * Wb[n*4 + 3];
    }
    __shared__ float red[6][256];
    #pragma unroll
    for (int j = 0; j < 6; ++j) red[j][t] = a[j];
    __syncthreads();
    for (int s = 128; s > 0; s >>= 1) {
        if (t < s) {
            #pragma unroll
            for (int j = 0; j < 6; ++j) red[j][t] += red[j][t + s];
        }
        __syncthreads();
    }
    if (t == 0) {
        float l0 = red[0][0] + bc[0], l1 = red[1][0] + bc[1];
        float mx = fmaxf(l0, l1);
        float e0 = expf(l0 - mx), e1 = expf(l1 - mx);
        float inv = 1.f / (e0 + e1);
        out[m*2 + 0] = e0 * inv;
        out[m*2 + 1] = e1 * inv;
        out[128 + m*4 + 0] = red[2][0] + bb[0];
        out[128 + m*4 + 1] = red[3][0] + bb[1];
        out[128 + m*4 + 2] = red[4][0] + bb[2];
        out[128 + m*4 + 3] = red[5][0] + bb[3];
    }
}

extern "C" void kernel_launch(void* const* d_in, const int* in_sizes, int n_in,
                              void* d_out, int out_size, void* d_ws, size_t ws_size,
                              hipStream_t stream) {
    const float* fm    = (const float*)d_in[0];
    const float* boxes = (const float*)d_in[1];
    const float* W1    = (const float*)d_in[2];
    const float* b1    = (const float*)d_in[3];
    const float* W2    = (const float*)d_in[4];
    const float* b2    = (const float*)d_in[5];
    const float* Wc    = (const float*)d_in[6];
    const float* bc    = (const float*)d_in[7];
    const float* Wb    = (const float*)d_in[8];
    const float* bb    = (const float*)d_in[9];
    float* out = (float*)d_out;
    char* ws = (char*)d_ws;

    const size_t XB  = (size_t)NROIS * DD * sizeof(unsigned short);   // 12,845,056
    const size_t P1B = (size_t)KC1 * MM * NN * sizeof(float);         // 25,690,112
    unsigned short* Xhi  = (unsigned short*)ws;
    unsigned short* Xlo  = (unsigned short*)(ws + XB);
    float*          P1   = (float*)(ws + 2 * XB);
    unsigned short* h1hi = (unsigned short*)(ws + 2 * XB + P1B);      // 131,072 B
    unsigned short* h1lo = (unsigned short*)(ws + 2 * XB + P1B + 131072);
    float*          P2   = (float*)(ws + 2 * XB + P1B + 262144);      // 4,194,304 B
    // total ~55.9 MB of d_ws

    crop_kernel<<<dim3(NROIS, SS*SS), 512, 0, stream>>>(fm, boxes, Xhi, Xlo);
    fc_mfma<<<dim3(4, KC1), 256, 0, stream>>>(Xhi, Xlo, W1, P1, DD, 1024);
    reduce_bias_split<<<(MM*NN)/256, 256, 0, stream>>>(P1, b1, h1hi, h1lo, KC1);
    fc_mfma<<<dim3(4, KC2), 256, 0, stream>>>(h1hi, h1lo, W2, P2, NN, 64);
    heads_kernel<<<NROIS, 256, 0, stream>>>(P2, b2, Wc, bc, Wb, bb, out);
}

// Round 7
// 197.599 us; speedup vs baseline: 1.7288x; 1.0764x over previous
//
#include <hip/hip_runtime.h>
#include <math.h>

#define SS 7
#define NROIS 64
#define CC 2048
#define DD (SS*SS*CC)   // 100352
#define MM 64
#define NN 1024
#define KC1 98          // k-chunks for fc1 (KCH=1024)
#define KC2 16          // k-chunks for fc2 (KCH=64)

typedef float f32x4 __attribute__((ext_vector_type(4)));
typedef __bf16 bf16x8 __attribute__((ext_vector_type(8)));

// Barrier WITHOUT the vmcnt(0) drain __syncthreads would emit: orders LDS
// (lgkmcnt(0)) but leaves register-destination global prefetches in flight
// across the barrier (T4 counted-wait pattern; compiler inserts its own
// vmcnt(N) before first use of prefetched registers).
#define LDS_BARRIER() do {                                         \
    asm volatile("s_waitcnt lgkmcnt(0)" ::: "memory");             \
    __builtin_amdgcn_s_barrier();                                  \
} while (0)

__device__ __forceinline__ unsigned short f2bf(float f){
    unsigned u = __builtin_bit_cast(unsigned, f);
    u += 0x7fffu + ((u >> 16) & 1u);           // RNE
    return (unsigned short)(u >> 16);
}
__device__ __forceinline__ float bf2f(unsigned short h){
    unsigned u = ((unsigned)h) << 16;
    return __builtin_bit_cast(float, u);
}
__device__ __forceinline__ void splitpk(float v0, float v1, unsigned& h, unsigned& l){
    __bf16 h0 = (__bf16)v0, h1 = (__bf16)v1;
    float r0 = v0 - (float)h0, r1 = v1 - (float)h1;
    __bf16 l0 = (__bf16)r0, l1 = (__bf16)r1;
    h = (unsigned)__builtin_bit_cast(unsigned short, h0) |
        ((unsigned)__builtin_bit_cast(unsigned short, h1) << 16);
    l = (unsigned)__builtin_bit_cast(unsigned short, l0) |
        ((unsigned)__builtin_bit_cast(unsigned short, l1) << 16);
}

// ---------------- Stage 1: crop + bilinear resize -> bf16 hi/lo planes ------
__global__ void crop_kernel(const float* __restrict__ fm,
                            const float* __restrict__ boxes,
                            unsigned short* __restrict__ Xhi,
                            unsigned short* __restrict__ Xlo) {
    int roi = blockIdx.x;
    int p   = blockIdx.y;         // 0..48
    int sy = p / SS, sx = p % SS;
    const float* b = boxes + roi * 4;
    float x1 = fmaxf(0.f, rintf(b[0]));
    float y1 = fmaxf(0.f, rintf(b[1]));
    float x2 = fminf(15.f, rintf(b[2]));
    float y2 = fminf(15.f, rintf(b[3]));
    float h = y2 - y1, w = x2 - x1;
    float iy = ((sy + 0.5f) * h) / 7.0f - 0.5f;
    float ix = ((sx + 0.5f) * w) / 7.0f - 0.5f;
    iy = fminf(fmaxf(iy, 0.f), h - 1.f);
    ix = fminf(fmaxf(ix, 0.f), w - 1.f);
    float y0 = floorf(iy), x0 = floorf(ix);
    float fy = iy - y0,   fx = ix - x0;
    int y0i = (int)(y1 + y0);
    int y1i = min(y0i + 1, (int)(y1 + h - 1.f));
    int x0i = (int)(x1 + x0);
    int x1i = min(x0i + 1, (int)(x1 + w - 1.f));

    int c = threadIdx.x * 4;
    const float4 v00 = *(const float4*)(fm + ((size_t)(y0i*16 + x0i))*CC + c);
    const float4 v01 = *(const float4*)(fm + ((size_t)(y0i*16 + x1i))*CC + c);
    const float4 v10 = *(const float4*)(fm + ((size_t)(y1i*16 + x0i))*CC + c);
    const float4 v11 = *(const float4*)(fm + ((size_t)(y1i*16 + x1i))*CC + c);
    float gy = 1.f - fy, gx = 1.f - fx;
    float o[4];
    o[0] = (v00.x*gy + v10.x*fy)*gx + (v01.x*gy + v11.x*fy)*fx;
    o[1] = (v00.y*gy + v10.y*fy)*gx + (v01.y*gy + v11.y*fy)*fx;
    o[2] = (v00.z*gy + v10.z*fy)*gx + (v01.z*gy + v11.z*fy)*fx;
    o[3] = (v00.w*gy + v10.w*fy)*gx + (v01.w*gy + v11.w*fy)*fx;
    uint2 hv, lv;
    splitpk(o[0], o[1], hv.x, lv.x);
    splitpk(o[2], o[3], hv.y, lv.y);
    size_t off = (size_t)roi*DD + (size_t)p*CC + c;
    *(uint2*)(Xhi + off) = hv;
    *(uint2*)(Xlo + off) = lv;
}

// ---------------- Stage 2: generic FC via bf16x2-split MFMA -----------------
// grid (4 n-tiles of 256, k-chunks). Block 64m x 256n, BK=32.
// W: reg->LDS transposed bf16 hi/lo, 2-deep prefetch; A: reg double-buffer.
// Barriers are NON-DRAINING (LDS_BARRIER) so prefetches pipeline across kt.
// 3-term: D += Ah*Bh + Ah*Bl + Al*Bh.
__global__ __launch_bounds__(256, 2)
void fc_mfma(const unsigned short* __restrict__ Ahi,
             const unsigned short* __restrict__ Alo,
             const float* __restrict__ Wm, float* __restrict__ P,
             int astride, int kchunk) {
    const int nb = blockIdx.x, kc = blockIdx.y;
    const int n0 = nb * 256;
    const int k0 = kc * kchunk;
    const int t = threadIdx.x;
    const int lane = t & 63, wv = t >> 6;
    const int ln = lane & 15;
    const int koff = (lane >> 4) * 8;        // k-offset within BK=32
    const int kp = t & 15, no = t >> 4;      // staging: k-pair, n-group of 16

    __shared__ unsigned short WTh[256][34];  // [n][k] transposed, hi
    __shared__ unsigned short WTl[256][34];  // lo

    f32x4 acc[16];                           // [nf*4+mf], static idx only
    #pragma unroll
    for (int i = 0; i < 16; ++i) acc[i] = (f32x4){0.f, 0.f, 0.f, 0.f};

    size_t arow[4];
    #pragma unroll
    for (int mf = 0; mf < 4; ++mf)
        arow[mf] = (size_t)(mf * 16 + ln) * astride;

    const float* wbase = Wm + (size_t)k0 * NN + n0 + no * 16;

    float4 wa[8], wb[8];                     // 2-deep W prefetch
    bf16x8 Aah[4], Aal[4], Abh[4], Abl[4];   // A double buffer

    auto loadW = [&](int kt, float4* r) {
        const float* p = wbase + (size_t)(kt * 32 + 2 * kp) * NN;
        #pragma unroll
        for (int j = 0; j < 4; ++j) {
            r[j]     = *(const float4*)(p + j * 4);        // row 2kp
            r[j + 4] = *(const float4*)(p + NN + j * 4);   // row 2kp+1
        }
    };
    auto loadA = [&](int kt, bf16x8* Ah, bf16x8* Al) {
        const size_t kk = (size_t)k0 + kt * 32 + koff;
        #pragma unroll
        for (int mf = 0; mf < 4; ++mf) {
            Ah[mf] = *(const bf16x8*)(Ahi + arow[mf] + kk);
            Al[mf] = *(const bf16x8*)(Alo + arow[mf] + kk);
        }
    };
    auto stageW = [&](const float4* r) {
        #pragma unroll
        for (int j = 0; j < 4; ++j) {
            #pragma unroll
            for (int e = 0; e < 4; ++e) {
                int n = no * 16 + j * 4 + e;
                unsigned h, l;
                splitpk(((const float*)&r[j])[e], ((const float*)&r[j + 4])[e], h, l);
                *(unsigned*)&WTh[n][2 * kp] = h;
                *(unsigned*)&WTl[n][2 * kp] = l;
            }
        }
    };

#define MFMA_PHASE(AH, AL)                                                     \
    {                                                                          \
        _Pragma("unroll")                                                      \
        for (int nf = 0; nf < 4; ++nf) {                                       \
            bf16x8 Bh = *(const bf16x8*)&WTh[wv * 64 + nf * 16 + ln][koff];    \
            bf16x8 Bl = *(const bf16x8*)&WTl[wv * 64 + nf * 16 + ln][koff];    \
            _Pragma("unroll")                                                  \
            for (int mf = 0; mf < 4; ++mf) {                                   \
                acc[nf*4+mf] = __builtin_amdgcn_mfma_f32_16x16x32_bf16(AH[mf], Bh, acc[nf*4+mf], 0, 0, 0); \
                acc[nf*4+mf] = __builtin_amdgcn_mfma_f32_16x16x32_bf16(AH[mf], Bl, acc[nf*4+mf], 0, 0, 0); \
                acc[nf*4+mf] = __builtin_amdgcn_mfma_f32_16x16x32_bf16(AL[mf], Bh, acc[nf*4+mf], 0, 0, 0); \
            }                                                                  \
        }                                                                      \
    }

    const int nkt = kchunk >> 5;             // BK=32: 32 (fc1) or 2 (fc2), even
    loadW(0, wa);
    loadW(1, wb);
    loadA(0, Aah, Aal);
    loadA(1, Abh, Abl);

    for (int ktp = 0; ktp < nkt; ktp += 2) {
        // ---- even tile ktp
        LDS_BARRIER();                       // LDS reuse safe; vmem stays in flight
        stageW(wa);                          // compiler waits vmcnt only for wa
        if (ktp + 2 < nkt) loadW(ktp + 2, wa);
        LDS_BARRIER();                       // ds_writes visible
        MFMA_PHASE(Aah, Aal);
        if (ktp + 2 < nkt) loadA(ktp + 2, Aah, Aal);
        // ---- odd tile ktp+1
        LDS_BARRIER();
        stageW(wb);
        if (ktp + 3 < nkt) loadW(ktp + 3, wb);
        LDS_BARRIER();
        MFMA_PHASE(Abh, Abl);
        if (ktp + 3 < nkt) loadA(ktp + 3, Abh, Abl);
    }
#undef MFMA_PHASE

    // ---- write partials: D row = (lane>>4)*4 + i, col = lane&15 (verified r2)
    const int orb = (lane >> 4) * 4;
    #pragma unroll
    for (int nf = 0; nf < 4; ++nf) {
        int col = n0 + wv * 64 + nf * 16 + ln;
        #pragma unroll
        for (int mf = 0; mf < 4; ++mf) {
            #pragma unroll
            for (int i = 0; i < 4; ++i) {
                int m = mf * 16 + orb + i;
                P[((size_t)kc * MM + m) * NN + col] = acc[nf*4+mf][i];
            }
        }
    }
}

// ---------------- Stage 3: reduce partials + bias + relu -> bf16 hi/lo ------
// 7 independent accumulators break the dependent-add latency chain (KC1=98=14*7).
__global__ void reduce_bias_split(const float* __restrict__ P,
                                  const float* __restrict__ bias,
                                  unsigned short* __restrict__ Yhi,
                                  unsigned short* __restrict__ Ylo) {
    int idx = blockIdx.x * 256 + threadIdx.x;   // 0..65535
    int n = idx & (NN - 1);
    float s0 = bias[n], s1 = 0.f, s2 = 0.f, s3 = 0.f, s4 = 0.f, s5 = 0.f, s6 = 0.f;
    for (int kc = 0; kc < KC1; kc += 7) {
        s0 += P[(size_t)(kc + 0) * (MM*NN) + idx];
        s1 += P[(size_t)(kc + 1) * (MM*NN) + idx];
        s2 += P[(size_t)(kc + 2) * (MM*NN) + idx];
        s3 += P[(size_t)(kc + 3) * (MM*NN) + idx];
        s4 += P[(size_t)(kc + 4) * (MM*NN) + idx];
        s5 += P[(size_t)(kc + 5) * (MM*NN) + idx];
        s6 += P[(size_t)(kc + 6) * (MM*NN) + idx];
    }
    float s = ((s0 + s1) + (s2 + s3)) + ((s4 + s5) + s6);
    s = fmaxf(s, 0.f);
    unsigned short h = f2bf(s);
    Yhi[idx] = h;
    Ylo[idx] = f2bf(s - bf2f(h));
}

// ---------------- Stage 4: fused P2-reduce + bias + relu + heads ------------
__global__ void heads_kernel(const float* __restrict__ P2,
                             const float* __restrict__ b2,
                             const float* __restrict__ Wc, const float* __restrict__ bc,
                             const float* __restrict__ Wb, const float* __restrict__ bb,
                             float* __restrict__ out) {
    int m = blockIdx.x;
    int t = threadIdx.x;   // 256
    float a[6] = {0,0,0,0,0,0};
    #pragma unroll
    for (int j = 0; j < 4; ++j) {
        int n = j * 256 + t;
        float s = b2[n];
        #pragma unroll
        for (int kc = 0; kc < KC2; ++kc)
            s += P2[((size_t)kc * MM + m) * NN + n];
        s = fmaxf(s, 0.f);
        a[0] += s * Wc[n*2 + 0];
        a[1] += s * Wc[n*2 + 1];
        a[2] += s * Wb[n*4 + 0];
        a[3] += s * Wb[n*4 + 1];
        a[4] += s * Wb[n*4 + 2];
        a[5] += s * Wb[n*4 + 3];
    }
    __shared__ float red[6][256];
    #pragma unroll
    for (int j = 0; j < 6; ++j) red[j][t] = a[j];
    __syncthreads();
    for (int s = 128; s > 0; s >>= 1) {
        if (t < s) {
            #pragma unroll
            for (int j = 0; j < 6; ++j) red[j][t] += red[j][t + s];
        }
        __syncthreads();
    }
    if (t == 0) {
        float l0 = red[0][0] + bc[0], l1 = red[1][0] + bc[1];
        float mx = fmaxf(l0, l1);
        float e0 = expf(l0 - mx), e1 = expf(l1 - mx);
        float inv = 1.f / (e0 + e1);
        out[m*2 + 0] = e0 * inv;
        out[m*2 + 1] = e1 * inv;
        out[128 + m*4 + 0] = red[2][0] + bb[0];
        out[128 + m*4 + 1] = red[3][0] + bb[1];
        out[128 + m*4 + 2] = red[4][0] + bb[2];
        out[128 + m*4 + 3] = red[5][0] + bb[3];
    }
}

extern "C" void kernel_launch(void* const* d_in, const int* in_sizes, int n_in,
                              void* d_out, int out_size, void* d_ws, size_t ws_size,
                              hipStream_t stream) {
    const float* fm    = (const float*)d_in[0];
    const float* boxes = (const float*)d_in[1];
    const float* W1    = (const float*)d_in[2];
    const float* b1    = (const float*)d_in[3];
    const float* W2    = (const float*)d_in[4];
    const float* b2    = (const float*)d_in[5];
    const float* Wc    = (const float*)d_in[6];
    const float* bc    = (const float*)d_in[7];
    const float* Wb    = (const float*)d_in[8];
    const float* bb    = (const float*)d_in[9];
    float* out = (float*)d_out;
    char* ws = (char*)d_ws;

    const size_t XB  = (size_t)NROIS * DD * sizeof(unsigned short);   // 12,845,056
    const size_t P1B = (size_t)KC1 * MM * NN * sizeof(float);         // 25,690,112
    unsigned short* Xhi  = (unsigned short*)ws;
    unsigned short* Xlo  = (unsigned short*)(ws + XB);
    float*          P1   = (float*)(ws + 2 * XB);
    unsigned short* h1hi = (unsigned short*)(ws + 2 * XB + P1B);      // 131,072 B
    unsigned short* h1lo = (unsigned short*)(ws + 2 * XB + P1B + 131072);
    float*          P2   = (float*)(ws + 2 * XB + P1B + 262144);      // 4,194,304 B

    crop_kernel<<<dim3(NROIS, SS*SS), 512, 0, stream>>>(fm, boxes, Xhi, Xlo);
    fc_mfma<<<dim3(4, KC1), 256, 0, stream>>>(Xhi, Xlo, W1, P1, DD, 1024);
    reduce_bias_split<<<(MM*NN)/256, 256, 0, stream>>>(P1, b1, h1hi, h1lo);
    fc_mfma<<<dim3(4, KC2), 256, 0, stream>>>(h1hi, h1lo, W2, P2, NN, 64);
    heads_kernel<<<NROIS, 256, 0, stream>>>(P2, b2, Wc, bc, Wb, bb, out);
}

// Round 8
// 192.189 us; speedup vs baseline: 1.7775x; 1.0282x over previous
//
#include <hip/hip_runtime.h>
#include <math.h>

#define SS 7
#define NROIS 64
#define CC 2048
#define DD (SS*SS*CC)   // 100352
#define MM 64
#define NN 1024
#define KC1 64          // fc1 k-chunks (KCH=1568, nkt=49)
#define KCH1 1568
#define KC2 16          // fc2 k-chunks (KCH=64, nkt=2)
#define KCH2 64

typedef float f32x4 __attribute__((ext_vector_type(4)));
typedef __bf16 bf16x8 __attribute__((ext_vector_type(8)));

// Barrier WITHOUT the vmcnt(0) drain __syncthreads would emit: orders LDS
// (lgkmcnt(0)) but leaves register-destination global prefetches in flight.
#define LDS_BARRIER() do {                                         \
    asm volatile("s_waitcnt lgkmcnt(0)" ::: "memory");             \
    __builtin_amdgcn_s_barrier();                                  \
} while (0)

__device__ __forceinline__ unsigned short f2bf(float f){
    unsigned u = __builtin_bit_cast(unsigned, f);
    u += 0x7fffu + ((u >> 16) & 1u);           // RNE
    return (unsigned short)(u >> 16);
}
__device__ __forceinline__ float bf2f(unsigned short h){
    unsigned u = ((unsigned)h) << 16;
    return __builtin_bit_cast(float, u);
}
__device__ __forceinline__ void splitpk(float v0, float v1, unsigned& h, unsigned& l){
    __bf16 h0 = (__bf16)v0, h1 = (__bf16)v1;
    float r0 = v0 - (float)h0, r1 = v1 - (float)h1;
    __bf16 l0 = (__bf16)r0, l1 = (__bf16)r1;
    h = (unsigned)__builtin_bit_cast(unsigned short, h0) |
        ((unsigned)__builtin_bit_cast(unsigned short, h1) << 16);
    l = (unsigned)__builtin_bit_cast(unsigned short, l0) |
        ((unsigned)__builtin_bit_cast(unsigned short, l1) << 16);
}

// A-plane layout: interleaved hi/lo, [row][k/8][hi:8 shorts | lo:8 shorts].
// Row stride (shorts) = 2*K. Fragment (row,k8): hi at row*2K + k8*16, lo +8.

// ---------------- Stage 1: crop + bilinear resize -> interleaved bf16 -------
__global__ void crop_kernel(const float* __restrict__ fm,
                            const float* __restrict__ boxes,
                            unsigned short* __restrict__ XI) {
    int roi = blockIdx.x;
    int p   = blockIdx.y;         // 0..48
    int sy = p / SS, sx = p % SS;
    const float* b = boxes + roi * 4;
    float x1 = fmaxf(0.f, rintf(b[0]));
    float y1 = fmaxf(0.f, rintf(b[1]));
    float x2 = fminf(15.f, rintf(b[2]));
    float y2 = fminf(15.f, rintf(b[3]));
    float h = y2 - y1, w = x2 - x1;
    float iy = ((sy + 0.5f) * h) / 7.0f - 0.5f;
    float ix = ((sx + 0.5f) * w) / 7.0f - 0.5f;
    iy = fminf(fmaxf(iy, 0.f), h - 1.f);
    ix = fminf(fmaxf(ix, 0.f), w - 1.f);
    float y0 = floorf(iy), x0 = floorf(ix);
    float fy = iy - y0,   fx = ix - x0;
    int y0i = (int)(y1 + y0);
    int y1i = min(y0i + 1, (int)(y1 + h - 1.f));
    int x0i = (int)(x1 + x0);
    int x1i = min(x0i + 1, (int)(x1 + w - 1.f));

    int c = threadIdx.x * 4;      // k index within row: p*CC + c
    const float4 v00 = *(const float4*)(fm + ((size_t)(y0i*16 + x0i))*CC + c);
    const float4 v01 = *(const float4*)(fm + ((size_t)(y0i*16 + x1i))*CC + c);
    const float4 v10 = *(const float4*)(fm + ((size_t)(y1i*16 + x0i))*CC + c);
    const float4 v11 = *(const float4*)(fm + ((size_t)(y1i*16 + x1i))*CC + c);
    float gy = 1.f - fy, gx = 1.f - fx;
    float o[4];
    o[0] = (v00.x*gy + v10.x*fy)*gx + (v01.x*gy + v11.x*fy)*fx;
    o[1] = (v00.y*gy + v10.y*fy)*gx + (v01.y*gy + v11.y*fy)*fx;
    o[2] = (v00.z*gy + v10.z*fy)*gx + (v01.z*gy + v11.z*fy)*fx;
    o[3] = (v00.w*gy + v10.w*fy)*gx + (v01.w*gy + v11.w*fy)*fx;
    uint2 hv, lv;
    splitpk(o[0], o[1], hv.x, lv.x);
    splitpk(o[2], o[3], hv.y, lv.y);
    int k = p * CC + c;
    size_t off = (size_t)roi * (2*DD) + (size_t)(k >> 3) * 16 + (k & 7);
    *(uint2*)(XI + off)     = hv;   // hi half of the 8-block
    *(uint2*)(XI + off + 8) = lv;   // lo half
}

// ---------------- Stage 2: generic FC via bf16x2-split MFMA -----------------
// grid (k-chunks, 8 n-tiles of 128) -- kc fastest so the 8 n-blocks sharing an
// X k-slice land on one XCD. Block 64m x 128n, BK=32, 4 waves (64m x 32n each).
// W: reg->LDS transposed bf16 hi/lo, 2-deep prefetch; A: reg double-buffer,
// interleaved planes. Non-draining barriers. nkt may be odd (>=2).
// 3-term: D += Ah*Bh + Ah*Bl + Al*Bh.
__global__ __launch_bounds__(256, 2)
void fc_mfma(const unsigned short* __restrict__ AI,
             const float* __restrict__ Wm, float* __restrict__ P,
             int rstride /*shorts, =2*K*/, int kchunk) {
    const int kc = blockIdx.x, nb = blockIdx.y;
    const int n0 = nb * 128;
    const int k0 = kc * kchunk;
    const int t = threadIdx.x;
    const int lane = t & 63, wv = t >> 6;
    const int ln = lane & 15;
    const int koff = (lane >> 4) * 8;        // k-offset within BK=32
    const int kp = t & 15, no = t >> 4;      // W staging: k-pair, n-group of 8

    __shared__ unsigned short WTh[128][34];  // [n][k] transposed, hi
    __shared__ unsigned short WTl[128][34];  // lo

    f32x4 acc[8];                            // [nf*4+mf], nf 0..1, mf 0..3
    #pragma unroll
    for (int i = 0; i < 8; ++i) acc[i] = (f32x4){0.f, 0.f, 0.f, 0.f};

    // A fragment base offsets (shorts): row mf*16+ln, k8 block of (k0+koff)
    size_t abase[4];
    #pragma unroll
    for (int mf = 0; mf < 4; ++mf)
        abase[mf] = (size_t)(mf * 16 + ln) * rstride + (size_t)((k0 + koff) >> 3) * 16;

    const float* wbase = Wm + (size_t)k0 * NN + n0 + no * 8;

    float4 wa[4], wb[4];                     // 2-deep W prefetch (16 fl each)
    bf16x8 Aah[4], Aal[4], Abh[4], Abl[4];   // A double buffer

    auto loadW = [&](int kt, float4* r) {
        const float* p = wbase + (size_t)(kt * 32 + 2 * kp) * NN;
        r[0] = *(const float4*)(p);          // row 2kp,   cols 0..3
        r[1] = *(const float4*)(p + 4);      // row 2kp,   cols 4..7
        r[2] = *(const float4*)(p + NN);     // row 2kp+1, cols 0..3
        r[3] = *(const float4*)(p + NN + 4); // row 2kp+1, cols 4..7
    };
    auto loadA = [&](int kt, bf16x8* Ah, bf16x8* Al) {
        const size_t kb = (size_t)kt * 64;   // kt*32 k-elems = kt*4 k8-blocks *16
        #pragma unroll
        for (int mf = 0; mf < 4; ++mf) {
            Ah[mf] = *(const bf16x8*)(AI + abase[mf] + kb);
            Al[mf] = *(const bf16x8*)(AI + abase[mf] + kb + 8);
        }
    };
    auto stageW = [&](const float4* r) {
        const float* r0 = (const float*)&r[0];   // row 2kp cols 0..7 (r[0],r[1])
        const float* r1 = (const float*)&r[2];   // row 2kp+1 cols 0..7
        #pragma unroll
        for (int e = 0; e < 8; ++e) {
            int n = no * 8 + e;
            unsigned h, l;
            splitpk(r0[e], r1[e], h, l);
            *(unsigned*)&WTh[n][2 * kp] = h;
            *(unsigned*)&WTl[n][2 * kp] = l;
        }
    };

#define MFMA_PHASE(AH, AL)                                                     \
    {                                                                          \
        _Pragma("unroll")                                                      \
        for (int nf = 0; nf < 2; ++nf) {                                       \
            bf16x8 Bh = *(const bf16x8*)&WTh[wv * 32 + nf * 16 + ln][koff];    \
            bf16x8 Bl = *(const bf16x8*)&WTl[wv * 32 + nf * 16 + ln][koff];    \
            _Pragma("unroll")                                                  \
            for (int mf = 0; mf < 4; ++mf) {                                   \
                acc[nf*4+mf] = __builtin_amdgcn_mfma_f32_16x16x32_bf16(AH[mf], Bh, acc[nf*4+mf], 0, 0, 0); \
                acc[nf*4+mf] = __builtin_amdgcn_mfma_f32_16x16x32_bf16(AH[mf], Bl, acc[nf*4+mf], 0, 0, 0); \
                acc[nf*4+mf] = __builtin_amdgcn_mfma_f32_16x16x32_bf16(AL[mf], Bh, acc[nf*4+mf], 0, 0, 0); \
            }                                                                  \
        }                                                                      \
    }

    const int nkt = kchunk >> 5;             // BK=32; requires nkt >= 2
    loadW(0, wa);
    loadW(1, wb);
    loadA(0, Aah, Aal);
    loadA(1, Abh, Abl);

    for (int ktp = 0; ktp + 1 < nkt; ktp += 2) {
        // ---- even tile ktp
        LDS_BARRIER();                       // vmem prefetches stay in flight
        stageW(wa);
        if (ktp + 2 < nkt) loadW(ktp + 2, wa);
        LDS_BARRIER();
        MFMA_PHASE(Aah, Aal);
        if (ktp + 2 < nkt) loadA(ktp + 2, Aah, Aal);
        // ---- odd tile ktp+1
        LDS_BARRIER();
        stageW(wb);
        if (ktp + 3 < nkt) loadW(ktp + 3, wb);
        LDS_BARRIER();
        MFMA_PHASE(Abh, Abl);
        if (ktp + 3 < nkt) loadA(ktp + 3, Abh, Abl);
    }
    if (nkt & 1) {                           // tail kt = nkt-1 (held in set A)
        LDS_BARRIER();
        stageW(wa);
        LDS_BARRIER();
        MFMA_PHASE(Aah, Aal);
    }
#undef MFMA_PHASE

    // ---- write partials: D row = (lane>>4)*4 + i, col = lane&15 (verified r2)
    const int orb = (lane >> 4) * 4;
    #pragma unroll
    for (int nf = 0; nf < 2; ++nf) {
        int col = n0 + wv * 32 + nf * 16 + ln;
        #pragma unroll
        for (int mf = 0; mf < 4; ++mf) {
            #pragma unroll
            for (int i = 0; i < 4; ++i) {
                int m = mf * 16 + orb + i;
                P[((size_t)kc * MM + m) * NN + col] = acc[nf*4+mf][i];
            }
        }
    }
}

// ---------------- Stage 3: reduce partials + bias + relu -> interleaved -----
// 8 independent accumulators (KC1=64=8*8) break the add latency chain.
__global__ void reduce_bias_split(const float* __restrict__ P,
                                  const float* __restrict__ bias,
                                  unsigned short* __restrict__ YI) {
    int idx = blockIdx.x * 256 + threadIdx.x;   // 0..65535
    int n = idx & (NN - 1);
    int m = idx >> 10;
    float s0 = bias[n], s1 = 0.f, s2 = 0.f, s3 = 0.f;
    float s4 = 0.f, s5 = 0.f, s6 = 0.f, s7 = 0.f;
    for (int kc = 0; kc < KC1; kc += 8) {
        s0 += P[(size_t)(kc + 0) * (MM*NN) + idx];
        s1 += P[(size_t)(kc + 1) * (MM*NN) + idx];
        s2 += P[(size_t)(kc + 2) * (MM*NN) + idx];
        s3 += P[(size_t)(kc + 3) * (MM*NN) + idx];
        s4 += P[(size_t)(kc + 4) * (MM*NN) + idx];
        s5 += P[(size_t)(kc + 5) * (MM*NN) + idx];
        s6 += P[(size_t)(kc + 6) * (MM*NN) + idx];
        s7 += P[(size_t)(kc + 7) * (MM*NN) + idx];
    }
    float s = ((s0 + s1) + (s2 + s3)) + ((s4 + s5) + (s6 + s7));
    s = fmaxf(s, 0.f);
    unsigned short h = f2bf(s);
    size_t off = (size_t)m * (2*NN) + (size_t)(n >> 3) * 16 + (n & 7);
    YI[off]     = h;
    YI[off + 8] = f2bf(s - bf2f(h));
}

// ---------------- Stage 4: fused P2-reduce + bias + relu + heads ------------
__global__ void heads_kernel(const float* __restrict__ P2,
                             const float* __restrict__ b2,
                             const float* __restrict__ Wc, const float* __restrict__ bc,
                             const float* __restrict__ Wb, const float* __restrict__ bb,
                             float* __restrict__ out) {
    int m = blockIdx.x;
    int t = threadIdx.x;   // 256
    float a[6] = {0,0,0,0,0,0};
    #pragma unroll
    for (int j = 0; j < 4; ++j) {
        int n = j * 256 + t;
        float s = b2[n];
        #pragma unroll
        for (int kc = 0; kc < KC2; ++kc)
            s += P2[((size_t)kc * MM + m) * NN + n];
        s = fmaxf(s, 0.f);
        a[0] += s * Wc[n*2 + 0];
        a[1] += s * Wc[n*2 + 1];
        a[2] += s * Wb[n*4 + 0];
        a[3] += s * Wb[n*4 + 1];
        a[4] += s * Wb[n*4 + 2];
        a[5] += s * Wb[n*4 + 3];
    }
    __shared__ float red[6][256];
    #pragma unroll
    for (int j = 0; j < 6; ++j) red[j][t] = a[j];
    __syncthreads();
    for (int s = 128; s > 0; s >>= 1) {
        if (t < s) {
            #pragma unroll
            for (int j = 0; j < 6; ++j) red[j][t] += red[j][t + s];
        }
        __syncthreads();
    }
    if (t == 0) {
        float l0 = red[0][0] + bc[0], l1 = red[1][0] + bc[1];
        float mx = fmaxf(l0, l1);
        float e0 = expf(l0 - mx), e1 = expf(l1 - mx);
        float inv = 1.f / (e0 + e1);
        out[m*2 + 0] = e0 * inv;
        out[m*2 + 1] = e1 * inv;
        out[128 + m*4 + 0] = red[2][0] + bb[0];
        out[128 + m*4 + 1] = red[3][0] + bb[1];
        out[128 + m*4 + 2] = red[4][0] + bb[2];
        out[128 + m*4 + 3] = red[5][0] + bb[3];
    }
}

extern "C" void kernel_launch(void* const* d_in, const int* in_sizes, int n_in,
                              void* d_out, int out_size, void* d_ws, size_t ws_size,
                              hipStream_t stream) {
    const float* fm    = (const float*)d_in[0];
    const float* boxes = (const float*)d_in[1];
    const float* W1    = (const float*)d_in[2];
    const float* b1    = (const float*)d_in[3];
    const float* W2    = (const float*)d_in[4];
    const float* b2    = (const float*)d_in[5];
    const float* Wc    = (const float*)d_in[6];
    const float* bc    = (const float*)d_in[7];
    const float* Wb    = (const float*)d_in[8];
    const float* bb    = (const float*)d_in[9];
    float* out = (float*)d_out;
    char* ws = (char*)d_ws;

    const size_t XIB = (size_t)NROIS * (2*DD) * sizeof(unsigned short);  // 25,690,112
    const size_t P1B = (size_t)KC1 * MM * NN * sizeof(float);            // 16,777,216
    unsigned short* XI  = (unsigned short*)ws;
    float*          P1  = (float*)(ws + XIB);
    unsigned short* h1I = (unsigned short*)(ws + XIB + P1B);             // 262,144 B
    float*          P2  = (float*)(ws + XIB + P1B + 262144);             // 4,194,304 B
    // total ~46.9 MB of d_ws (ws is ~1.6 GB per poison WRITE_SIZE)

    crop_kernel<<<dim3(NROIS, SS*SS), 512, 0, stream>>>(fm, boxes, XI);
    fc_mfma<<<dim3(KC1, 8), 256, 0, stream>>>(XI, W1, P1, 2*DD, KCH1);
    reduce_bias_split<<<(MM*NN)/256, 256, 0, stream>>>(P1, b1, h1I);
    fc_mfma<<<dim3(KC2, 8), 256, 0, stream>>>(h1I, W2, P2, 2*NN, KCH2);
    heads_kernel<<<NROIS, 256, 0, stream>>>(P2, b2, Wc, bc, Wb, bb, out);
}

// Round 9
// 180.174 us; speedup vs baseline: 1.8960x; 1.0667x over previous
//
#include <hip/hip_runtime.h>
#include <math.h>

#define SS 7
#define NROIS 64
#define CC 2048
#define DD (SS*SS*CC)   // 100352
#define MM 64
#define NN 1024
#define NP1 256         // fc1 partials (one per block)
#define KC2 16          // fc2 k-chunks (KCH=64, nkt=2)
#define KCH2 64
#define WSROW 1026      // fc1 LDS row stride in dwords (32 rows)
#define FC1_LDS (32 * WSROW * 4)   // 131,328 B dynamic

typedef float f32x4 __attribute__((ext_vector_type(4)));
typedef __bf16 bf16x8 __attribute__((ext_vector_type(8)));
typedef unsigned int uintx4 __attribute__((ext_vector_type(4)));

// Barrier WITHOUT the vmcnt(0) drain __syncthreads would emit: orders LDS
// (lgkmcnt(0)) but leaves register-destination global prefetches in flight.
#define LDS_BARRIER() do {                                         \
    asm volatile("s_waitcnt lgkmcnt(0)" ::: "memory");             \
    __builtin_amdgcn_s_barrier();                                  \
} while (0)

__device__ __forceinline__ unsigned short f2bf(float f){
    unsigned u = __builtin_bit_cast(unsigned, f);
    u += 0x7fffu + ((u >> 16) & 1u);           // RNE
    return (unsigned short)(u >> 16);
}
__device__ __forceinline__ float bf2f(unsigned short h){
    unsigned u = ((unsigned)h) << 16;
    return __builtin_bit_cast(float, u);
}
__device__ __forceinline__ void splitpk(float v0, float v1, unsigned& h, unsigned& l){
    __bf16 h0 = (__bf16)v0, h1 = (__bf16)v1;
    float r0 = v0 - (float)h0, r1 = v1 - (float)h1;
    __bf16 l0 = (__bf16)r0, l1 = (__bf16)r1;
    h = (unsigned)__builtin_bit_cast(unsigned short, h0) |
        ((unsigned)__builtin_bit_cast(unsigned short, h1) << 16);
    l = (unsigned)__builtin_bit_cast(unsigned short, l0) |
        ((unsigned)__builtin_bit_cast(unsigned short, l1) << 16);
}

// A-plane layout: interleaved hi/lo, [row][k/8][hi:8 shorts | lo:8 shorts].

// ---------------- Stage 1: crop + bilinear resize -> interleaved bf16 -------
__global__ void crop_kernel(const float* __restrict__ fm,
                            const float* __restrict__ boxes,
                            unsigned short* __restrict__ XI) {
    int roi = blockIdx.x;
    int p   = blockIdx.y;         // 0..48
    int sy = p / SS, sx = p % SS;
    const float* b = boxes + roi * 4;
    float x1 = fmaxf(0.f, rintf(b[0]));
    float y1 = fmaxf(0.f, rintf(b[1]));
    float x2 = fminf(15.f, rintf(b[2]));
    float y2 = fminf(15.f, rintf(b[3]));
    float h = y2 - y1, w = x2 - x1;
    float iy = ((sy + 0.5f) * h) / 7.0f - 0.5f;
    float ix = ((sx + 0.5f) * w) / 7.0f - 0.5f;
    iy = fminf(fmaxf(iy, 0.f), h - 1.f);
    ix = fminf(fmaxf(ix, 0.f), w - 1.f);
    float y0 = floorf(iy), x0 = floorf(ix);
    float fy = iy - y0,   fx = ix - x0;
    int y0i = (int)(y1 + y0);
    int y1i = min(y0i + 1, (int)(y1 + h - 1.f));
    int x0i = (int)(x1 + x0);
    int x1i = min(x0i + 1, (int)(x1 + w - 1.f));

    int c = threadIdx.x * 4;      // k index within row: p*CC + c
    const float4 v00 = *(const float4*)(fm + ((size_t)(y0i*16 + x0i))*CC + c);
    const float4 v01 = *(const float4*)(fm + ((size_t)(y0i*16 + x1i))*CC + c);
    const float4 v10 = *(const float4*)(fm + ((size_t)(y1i*16 + x0i))*CC + c);
    const float4 v11 = *(const float4*)(fm + ((size_t)(y1i*16 + x1i))*CC + c);
    float gy = 1.f - fy, gx = 1.f - fx;
    float o[4];
    o[0] = (v00.x*gy + v10.x*fy)*gx + (v01.x*gy + v11.x*fy)*fx;
    o[1] = (v00.y*gy + v10.y*fy)*gx + (v01.y*gy + v11.y*fy)*fx;
    o[2] = (v00.z*gy + v10.z*fy)*gx + (v01.z*gy + v11.z*fy)*fx;
    o[3] = (v00.w*gy + v10.w*fy)*gx + (v01.w*gy + v11.w*fy)*fx;
    uint2 hv, lv;
    splitpk(o[0], o[1], hv.x, lv.x);
    splitpk(o[2], o[3], hv.y, lv.y);
    int k = p * CC + c;
    size_t off = (size_t)roi * (2*DD) + (size_t)(k >> 3) * 16 + (k & 7);
    *(uint2*)(XI + off)     = hv;
    *(uint2*)(XI + off + 8) = lv;
}

// ---------------- Stage 2a: fc1 full-row k-split stream GEMM ----------------
// 256 blocks (1/CU), 512 thr = 8 waves. Block tile 64m x 1024n (FULL W rows:
// each block streams one contiguous ~1.6MB W region). Block kc owns k-tiles
// [start, start+cnt) of 32 (cnt = 12 or 13). W staged fp32 in dynamic LDS
// [32][1026] (b64 writes conflict-free; stride!=0 mod 32 => 2-way col reads);
// bf16 hi/lo split at READ time. Quarter-tile reg prefetch, non-draining
// barriers. Wave w: n in [w*128, w*128+128), 4mf x 8nf frags.
__global__ __launch_bounds__(512, 2)
void fc1_stream(const unsigned short* __restrict__ AI,
                const float* __restrict__ Wm, float* __restrict__ P) {
    const int kc = blockIdx.x;                       // 0..255
    const int kt_cnt = 12 + (kc < 64 ? 1 : 0);
    const int k0 = (kc * 12 + (kc < 64 ? kc : 64)) * 32;

    const int t = threadIdx.x;                       // 0..511
    const int lane = t & 63, wv = t >> 6;
    const int ln = lane & 15;
    const int koff = (lane >> 4) * 8;

    extern __shared__ float WS[];                    // [32][WSROW]

    f32x4 acc[32];                                   // [nf*4+mf], static only
    #pragma unroll
    for (int i = 0; i < 32; ++i) acc[i] = (f32x4){0.f, 0.f, 0.f, 0.f};

    // A fragment bases (shorts): row mf*16+ln, interleaved layout
    size_t abase[4];
    #pragma unroll
    for (int mf = 0; mf < 4; ++mf)
        abase[mf] = (size_t)(mf * 16 + ln) * (2*DD) + (size_t)(k0 + koff) * 2;

    bf16x8 Ah[4], Al[4];
    auto issueA = [&](int kt) {
        #pragma unroll
        for (int mf = 0; mf < 4; ++mf) {
            Ah[mf] = *(const bf16x8*)(AI + abase[mf] + (size_t)kt * 64);
            Al[mf] = *(const bf16x8*)(AI + abase[mf] + (size_t)kt * 64 + 8);
        }
    };

    // W quarter tiles: quarter q = rows q*8..q*8+7 of the 32-row k-tile.
    float4 R0[4], R1[4];
    auto issueWq = [&](int kt, int q, float4* R) {
        if (kt >= kt_cnt) return;
        const float* base = Wm + (size_t)(k0 + kt * 32 + q * 8) * NN;
        #pragma unroll
        for (int i = 0; i < 4; ++i) {
            int lin = t + i * 512;                   // 0..2047
            int row = lin >> 8, col4 = lin & 255;
            R[i] = *(const float4*)(base + (size_t)row * NN + col4 * 4);
        }
    };
    auto stageWq = [&](int q, const float4* R) {
        #pragma unroll
        for (int i = 0; i < 4; ++i) {
            int lin = t + i * 512;
            int row = q * 8 + (lin >> 8), col4 = lin & 255;
            float* p = &WS[row * WSROW + col4 * 4];
            *(float2*)(p)     = (float2){R[i].x, R[i].y};   // ds_write_b64
            *(float2*)(p + 2) = (float2){R[i].z, R[i].w};
        }
    };

    issueWq(0, 0, R0);
    issueWq(0, 1, R1);

    for (int kt = 0; kt < kt_cnt; ++kt) {
        LDS_BARRIER();                               // WS free for reuse
        issueA(kt);                                  // hides under W wait
        stageWq(0, R0); issueWq(kt, 2, R0);
        stageWq(1, R1); issueWq(kt, 3, R1);
        stageWq(2, R0); issueWq(kt + 1, 0, R0);
        stageWq(3, R1); issueWq(kt + 1, 1, R1);
        LDS_BARRIER();                               // ds_writes visible
        // compute: B from fp32 LDS with read-time hi/lo split
        const int dwb = koff * WSROW + wv * 128 + ln;
        #pragma unroll
        for (int nf = 0; nf < 8; ++nf) {
            float f0 = WS[dwb + 0*WSROW + nf*16];
            float f1 = WS[dwb + 1*WSROW + nf*16];
            float f2 = WS[dwb + 2*WSROW + nf*16];
            float f3 = WS[dwb + 3*WSROW + nf*16];
            float f4 = WS[dwb + 4*WSROW + nf*16];
            float f5 = WS[dwb + 5*WSROW + nf*16];
            float f6 = WS[dwb + 6*WSROW + nf*16];
            float f7 = WS[dwb + 7*WSROW + nf*16];
            unsigned h01,l01,h23,l23,h45,l45,h67,l67;
            splitpk(f0, f1, h01, l01);
            splitpk(f2, f3, h23, l23);
            splitpk(f4, f5, h45, l45);
            splitpk(f6, f7, h67, l67);
            bf16x8 Bh = __builtin_bit_cast(bf16x8, (uintx4){h01, h23, h45, h67});
            bf16x8 Bl = __builtin_bit_cast(bf16x8, (uintx4){l01, l23, l45, l67});
            #pragma unroll
            for (int mf = 0; mf < 4; ++mf) {
                acc[nf*4+mf] = __builtin_amdgcn_mfma_f32_16x16x32_bf16(Ah[mf], Bh, acc[nf*4+mf], 0, 0, 0);
                acc[nf*4+mf] = __builtin_amdgcn_mfma_f32_16x16x32_bf16(Ah[mf], Bl, acc[nf*4+mf], 0, 0, 0);
                acc[nf*4+mf] = __builtin_amdgcn_mfma_f32_16x16x32_bf16(Al[mf], Bh, acc[nf*4+mf], 0, 0, 0);
            }
        }
    }

    // ---- write partials: D row = (lane>>4)*4 + i, col = lane&15 (verified)
    const int orb = (lane >> 4) * 4;
    #pragma unroll
    for (int nf = 0; nf < 8; ++nf) {
        int col = wv * 128 + nf * 16 + ln;
        #pragma unroll
        for (int mf = 0; mf < 4; ++mf) {
            #pragma unroll
            for (int i = 0; i < 4; ++i) {
                int m = mf * 16 + orb + i;
                P[((size_t)kc * MM + m) * NN + col] = acc[nf*4+mf][i];
            }
        }
    }
}

// ---------------- Stage 2b: generic FC (fc2) via bf16x2-split MFMA ----------
__global__ __launch_bounds__(256, 2)
void fc_mfma(const unsigned short* __restrict__ AI,
             const float* __restrict__ Wm, float* __restrict__ P,
             int rstride /*shorts*/, int kchunk) {
    const int kc = blockIdx.x, nb = blockIdx.y;
    const int n0 = nb * 128;
    const int k0 = kc * kchunk;
    const int t = threadIdx.x;
    const int lane = t & 63, wv = t >> 6;
    const int ln = lane & 15;
    const int koff = (lane >> 4) * 8;
    const int kp = t & 15, no = t >> 4;

    __shared__ unsigned short WTh[128][34];
    __shared__ unsigned short WTl[128][34];

    f32x4 acc[8];
    #pragma unroll
    for (int i = 0; i < 8; ++i) acc[i] = (f32x4){0.f, 0.f, 0.f, 0.f};

    size_t abase[4];
    #pragma unroll
    for (int mf = 0; mf < 4; ++mf)
        abase[mf] = (size_t)(mf * 16 + ln) * rstride + (size_t)((k0 + koff) >> 3) * 16;

    const float* wbase = Wm + (size_t)k0 * NN + n0 + no * 8;

    float4 wa[4], wb[4];
    bf16x8 Aah[4], Aal[4], Abh[4], Abl[4];

    auto loadW = [&](int kt, float4* r) {
        const float* p = wbase + (size_t)(kt * 32 + 2 * kp) * NN;
        r[0] = *(const float4*)(p);
        r[1] = *(const float4*)(p + 4);
        r[2] = *(const float4*)(p + NN);
        r[3] = *(const float4*)(p + NN + 4);
    };
    auto loadA = [&](int kt, bf16x8* Ah, bf16x8* Al) {
        const size_t kb = (size_t)kt * 64;
        #pragma unroll
        for (int mf = 0; mf < 4; ++mf) {
            Ah[mf] = *(const bf16x8*)(AI + abase[mf] + kb);
            Al[mf] = *(const bf16x8*)(AI + abase[mf] + kb + 8);
        }
    };
    auto stageW = [&](const float4* r) {
        const float* r0 = (const float*)&r[0];
        const float* r1 = (const float*)&r[2];
        #pragma unroll
        for (int e = 0; e < 8; ++e) {
            int n = no * 8 + e;
            unsigned h, l;
            splitpk(r0[e], r1[e], h, l);
            *(unsigned*)&WTh[n][2 * kp] = h;
            *(unsigned*)&WTl[n][2 * kp] = l;
        }
    };

#define MFMA_PHASE(AH, AL)                                                     \
    {                                                                          \
        _Pragma("unroll")                                                      \
        for (int nf = 0; nf < 2; ++nf) {                                       \
            bf16x8 Bh = *(const bf16x8*)&WTh[wv * 32 + nf * 16 + ln][koff];    \
            bf16x8 Bl = *(const bf16x8*)&WTl[wv * 32 + nf * 16 + ln][koff];    \
            _Pragma("unroll")                                                  \
            for (int mf = 0; mf < 4; ++mf) {                                   \
                acc[nf*4+mf] = __builtin_amdgcn_mfma_f32_16x16x32_bf16(AH[mf], Bh, acc[nf*4+mf], 0, 0, 0); \
                acc[nf*4+mf] = __builtin_amdgcn_mfma_f32_16x16x32_bf16(AH[mf], Bl, acc[nf*4+mf], 0, 0, 0); \
                acc[nf*4+mf] = __builtin_amdgcn_mfma_f32_16x16x32_bf16(AL[mf], Bh, acc[nf*4+mf], 0, 0, 0); \
            }                                                                  \
        }                                                                      \
    }

    const int nkt = kchunk >> 5;
    loadW(0, wa);
    loadW(1, wb);
    loadA(0, Aah, Aal);
    loadA(1, Abh, Abl);

    for (int ktp = 0; ktp + 1 < nkt; ktp += 2) {
        LDS_BARRIER();
        stageW(wa);
        if (ktp + 2 < nkt) loadW(ktp + 2, wa);
        LDS_BARRIER();
        MFMA_PHASE(Aah, Aal);
        if (ktp + 2 < nkt) loadA(ktp + 2, Aah, Aal);
        LDS_BARRIER();
        stageW(wb);
        if (ktp + 3 < nkt) loadW(ktp + 3, wb);
        LDS_BARRIER();
        MFMA_PHASE(Abh, Abl);
        if (ktp + 3 < nkt) loadA(ktp + 3, Abh, Abl);
    }
    if (nkt & 1) {
        LDS_BARRIER();
        stageW(wa);
        LDS_BARRIER();
        MFMA_PHASE(Aah, Aal);
    }
#undef MFMA_PHASE

    const int orb = (lane >> 4) * 4;
    #pragma unroll
    for (int nf = 0; nf < 2; ++nf) {
        int col = n0 + wv * 32 + nf * 16 + ln;
        #pragma unroll
        for (int mf = 0; mf < 4; ++mf) {
            #pragma unroll
            for (int i = 0; i < 4; ++i) {
                int m = mf * 16 + orb + i;
                P[((size_t)kc * MM + m) * NN + col] = acc[nf*4+mf][i];
            }
        }
    }
}

// ---------------- Stage 3: reduce 256 partials + bias + relu -> interleaved -
__global__ void reduce_bias_split(const float* __restrict__ P,
                                  const float* __restrict__ bias,
                                  unsigned short* __restrict__ YI) {
    int idx = blockIdx.x * 256 + threadIdx.x;   // 0..65535
    int n = idx & (NN - 1);
    int m = idx >> 10;
    float s0 = bias[n], s1 = 0.f, s2 = 0.f, s3 = 0.f;
    float s4 = 0.f, s5 = 0.f, s6 = 0.f, s7 = 0.f;
    for (int kc = 0; kc < NP1; kc += 8) {
        s0 += P[(size_t)(kc + 0) * (MM*NN) + idx];
        s1 += P[(size_t)(kc + 1) * (MM*NN) + idx];
        s2 += P[(size_t)(kc + 2) * (MM*NN) + idx];
        s3 += P[(size_t)(kc + 3) * (MM*NN) + idx];
        s4 += P[(size_t)(kc + 4) * (MM*NN) + idx];
        s5 += P[(size_t)(kc + 5) * (MM*NN) + idx];
        s6 += P[(size_t)(kc + 6) * (MM*NN) + idx];
        s7 += P[(size_t)(kc + 7) * (MM*NN) + idx];
    }
    float s = ((s0 + s1) + (s2 + s3)) + ((s4 + s5) + (s6 + s7));
    s = fmaxf(s, 0.f);
    unsigned short h = f2bf(s);
    size_t off = (size_t)m * (2*NN) + (size_t)(n >> 3) * 16 + (n & 7);
    YI[off]     = h;
    YI[off + 8] = f2bf(s - bf2f(h));
}

// ---------------- Stage 4: fused P2-reduce + bias + relu + heads ------------
__global__ void heads_kernel(const float* __restrict__ P2,
                             const float* __restrict__ b2,
                             const float* __restrict__ Wc, const float* __restrict__ bc,
                             const float* __restrict__ Wb, const float* __restrict__ bb,
                             float* __restrict__ out) {
    int m = blockIdx.x;
    int t = threadIdx.x;   // 256
    float a[6] = {0,0,0,0,0,0};
    #pragma unroll
    for (int j = 0; j < 4; ++j) {
        int n = j * 256 + t;
        float s = b2[n];
        #pragma unroll
        for (int kc = 0; kc < KC2; ++kc)
            s += P2[((size_t)kc * MM + m) * NN + n];
        s = fmaxf(s, 0.f);
        a[0] += s * Wc[n*2 + 0];
        a[1] += s * Wc[n*2 + 1];
        a[2] += s * Wb[n*4 + 0];
        a[3] += s * Wb[n*4 + 1];
        a[4] += s * Wb[n*4 + 2];
        a[5] += s * Wb[n*4 + 3];
    }
    __shared__ float red[6][256];
    #pragma unroll
    for (int j = 0; j < 6; ++j) red[j][t] = a[j];
    __syncthreads();
    for (int s = 128; s > 0; s >>= 1) {
        if (t < s) {
            #pragma unroll
            for (int j = 0; j < 6; ++j) red[j][t] += red[j][t + s];
        }
        __syncthreads();
    }
    if (t == 0) {
        float l0 = red[0][0] + bc[0], l1 = red[1][0] + bc[1];
        float mx = fmaxf(l0, l1);
        float e0 = expf(l0 - mx), e1 = expf(l1 - mx);
        float inv = 1.f / (e0 + e1);
        out[m*2 + 0] = e0 * inv;
        out[m*2 + 1] = e1 * inv;
        out[128 + m*4 + 0] = red[2][0] + bb[0];
        out[128 + m*4 + 1] = red[3][0] + bb[1];
        out[128 + m*4 + 2] = red[4][0] + bb[2];
        out[128 + m*4 + 3] = red[5][0] + bb[3];
    }
}

extern "C" void kernel_launch(void* const* d_in, const int* in_sizes, int n_in,
                              void* d_out, int out_size, void* d_ws, size_t ws_size,
                              hipStream_t stream) {
    const float* fm    = (const float*)d_in[0];
    const float* boxes = (const float*)d_in[1];
    const float* W1    = (const float*)d_in[2];
    const float* b1    = (const float*)d_in[3];
    const float* W2    = (const float*)d_in[4];
    const float* b2    = (const float*)d_in[5];
    const float* Wc    = (const float*)d_in[6];
    const float* bc    = (const float*)d_in[7];
    const float* Wb    = (const float*)d_in[8];
    const float* bb    = (const float*)d_in[9];
    float* out = (float*)d_out;
    char* ws = (char*)d_ws;

    const size_t XIB = (size_t)NROIS * (2*DD) * sizeof(unsigned short);  // 25,690,112
    const size_t P1B = (size_t)NP1 * MM * NN * sizeof(float);            // 67,108,864
    unsigned short* XI  = (unsigned short*)ws;
    float*          P1  = (float*)(ws + XIB);
    unsigned short* h1I = (unsigned short*)(ws + XIB + P1B);             // 262,144 B
    float*          P2  = (float*)(ws + XIB + P1B + 262144);             // 4,194,304 B
    // total ~97.3 MB of d_ws

    // opt-in to >64 KB dynamic LDS for fc1 (idempotent, host-side, capture-safe)
    hipFuncSetAttribute((const void*)fc1_stream,
                        hipFuncAttributeMaxDynamicSharedMemorySize, FC1_LDS);

    crop_kernel<<<dim3(NROIS, SS*SS), 512, 0, stream>>>(fm, boxes, XI);
    fc1_stream<<<NP1, 512, FC1_LDS, stream>>>(XI, W1, P1);
    reduce_bias_split<<<(MM*NN)/256, 256, 0, stream>>>(P1, b1, h1I);
    fc_mfma<<<dim3(KC2, 8), 256, 0, stream>>>(h1I, W2, P2, 2*NN, KCH2);
    heads_kernel<<<NROIS, 256, 0, stream>>>(P2, b2, Wc, bc, Wb, bb, out);
}